// Round 12
// baseline (123.992 us; speedup 1.0000x reference)
//
#include <hip/hip_runtime.h>
#include <hip/hip_bf16.h>

typedef __bf16 bf16_t;
typedef __bf16 bf16x4 __attribute__((ext_vector_type(4)));
typedef __bf16 bf16x8 __attribute__((ext_vector_type(8)));
typedef float  f32x4  __attribute__((ext_vector_type(4)));

#define NB 4096
#define IN_DIM 256
#define HID 512
#define SUB 256
#define GRID_ 32

// ---------------- math helpers ----------------
__device__ __forceinline__ float fract_f(float x) {
#if __has_builtin(__builtin_amdgcn_fractf)
  return __builtin_amdgcn_fractf(x);
#else
  return x - floorf(x);
#endif
}
__device__ __forceinline__ float cos_rev(float rev) {
#if __has_builtin(__builtin_amdgcn_cosf)
  return __builtin_amdgcn_cosf(rev);
#else
  return __cosf(rev * 6.283185307179586f);
#endif
}
__device__ __forceinline__ float sin_rev(float rev) {
#if __has_builtin(__builtin_amdgcn_sinf)
  return __builtin_amdgcn_sinf(rev);
#else
  return __sinf(rev * 6.283185307179586f);
#endif
}
__device__ __forceinline__ float sigm(float v) { return 1.f / (1.f + __expf(-v)); }
__device__ __forceinline__ float fast_tanh(float x) {
  float e = __expf(2.f * x);
  return (e - 1.f) / (e + 1.f);
}
#define INV2PI 0.15915494309189535f

// ---------------- workspace layout (bytes), high-water 59.77MB ----------------
#define O_XHI   0ull
#define O_XLO   2097152ull
#define O_H0    4194304ull
#define O_S0H   8388608ull
#define O_S0L   10485760ull
#define O_FCB   12582912ull   // fcb2 tiled layout, 8.4MB
#define O_KT    20971520ull
#define O_RKT   21757952ull
#define O_AWT   23330816ull
#define O_KXH   23592960ull
#define O_KXL   23724032ull
#define O_KHH   23855104ull
#define O_KHL   23986176ull
#define O_TC    24117248ull
#define O_SOB   32505856ull
#define O_AGG   34603008ull
#define O_P3    38797312ull   // chunks 3..7, 5 x 4MB -> end 59768832

// ---------------- transpose-convert body ----------------
__device__ __forceinline__ void tconv_body(const float* __restrict__ src,
                                           bf16_t* __restrict__ hi,
                                           bf16_t* __restrict__ lo,
                                           int R, int C, int bx, int by,
                                           bool wantlo, float scale) {
  __shared__ float t[32][33];
  int c0 = bx * 32, r0 = by * 32;
  int tx = threadIdx.x & 31, ty = threadIdx.x >> 5;
#pragma unroll
  for (int rr = 0; rr < 4; rr++) {
    int r = ty + rr * 8;
    t[r][tx] = src[(size_t)(r0 + r) * C + c0 + tx];
  }
  __syncthreads();
#pragma unroll
  for (int rr = 0; rr < 4; rr++) {
    int cl = ty + rr * 8;
    float f = t[tx][cl] * scale;
    bf16_t h = (bf16_t)f;
    size_t oi = (size_t)(c0 + cl) * R + r0 + tx;
    hi[oi] = h;
    if (wantlo) lo[oi] = (bf16_t)(f - (float)h);
  }
}

// ---------------- fused prep (conversions + fcb2 tiling) + all transposes ----
__global__ __launch_bounds__(256) void k_prep(const float* __restrict__ x,
                                              const float* __restrict__ h0,
                                              const float* __restrict__ s0,
                                              const float* __restrict__ fc,
                                              const float* __restrict__ Wk,
                                              const float* __restrict__ Wr,
                                              const float* __restrict__ aw,
                                              const float* __restrict__ kx,
                                              const float* __restrict__ kh,
                                              bf16_t* __restrict__ xhi, bf16_t* __restrict__ xlo,
                                              bf16_t* __restrict__ h0b,
                                              bf16_t* __restrict__ s0h, bf16_t* __restrict__ s0l,
                                              bf16_t* __restrict__ fcb2,
                                              bf16_t* __restrict__ kt,
                                              bf16_t* __restrict__ rkt,
                                              bf16_t* __restrict__ awt,
                                              bf16_t* __restrict__ kxh, bf16_t* __restrict__ kxl,
                                              bf16_t* __restrict__ khh, bf16_t* __restrict__ khl) {
  int bid = blockIdx.x;
  if (bid < 2048) {
    for (int q = bid * 256 + threadIdx.x; q < 2097152; q += 524288) {
      if (q < 1048576) {
        const float* src; bf16_t* hi; bf16_t* lo = nullptr; int base;
        if (q < 262144)       { src = x;  hi = xhi; lo = xlo; base = q; }
        else if (q < 786432)  { src = h0; hi = h0b;           base = q - 262144; }
        else                  { src = s0; hi = s0h; lo = s0l; base = q - 786432; }
        float4 v = *(const float4*)(src + (size_t)base * 4);
        bf16x4 h; h[0] = (bf16_t)v.x; h[1] = (bf16_t)v.y; h[2] = (bf16_t)v.z; h[3] = (bf16_t)v.w;
        *(bf16x4*)(hi + (size_t)base * 4) = h;
        if (lo) {
          bf16x4 l;
          l[0] = (bf16_t)(v.x - (float)h[0]); l[1] = (bf16_t)(v.y - (float)h[1]);
          l[2] = (bf16_t)(v.z - (float)h[2]); l[3] = (bf16_t)(v.w - (float)h[3]);
          *(bf16x4*)(lo + (size_t)base * 4) = l;
        }
      } else {
        int f = q - 1048576;              // fc quad
        int e = f * 4;
        int g = e & 31, i = (e >> 5) & 255, o = (e >> 13) & 255, s = e >> 21;
        float4 v = *(const float4*)(fc + (size_t)e);
        bf16x4 h; h[0] = (bf16_t)v.x; h[1] = (bf16_t)v.y; h[2] = (bf16_t)v.z; h[3] = (bf16_t)v.w;
        int nb = o >> 7, wn = (o >> 6) & 1, j = (o >> 4) & 3, lr = o & 15;
        int g4 = g >> 3, t0 = g & 7;
        size_t idx = ((((((size_t)(i * 2 + nb) * 2 + wn) * 4 + j) * 2 + s) * 4 + g4) * 16 + lr) * 8 + t0;
        *(bf16x4*)(fcb2 + idx) = h;
      }
    }
  } else {
    int b = bid - 2048;
    if (b < 384)       { tconv_body(Wk, kt,  nullptr, 256, 1536, b % 48, b / 48, false, 1.f); }
    else if (b < 1152) { b -= 384;  tconv_body(Wr, rkt, nullptr, 512, 1536, b % 48, b / 48, false, 1.f); }
    else if (b < 1280) { b -= 1152; tconv_body(aw, awt, nullptr, 256, 512,  b % 16, b / 16, false, 1.f); }
    else if (b < 1344) { b -= 1280; tconv_body(kx, kxh, kxl,     256, 256,  b % 8,  b / 8,  true, INV2PI); }
    else               { b -= 1344; tconv_body(kh, khh, khl,     256, 256,  b % 8,  b / 8,  true, INV2PI); }
  }
}

// ---------------- generic multi-pass bf16 MFMA GEMM (stride 64 + XOR swz) ---
struct Pass { const bf16_t* A; const bf16_t* Bt; int K; int lda; int ldbt; };
struct GArgs {
  Pass p[6]; int np;
  const float* bias;
  int act;
  float* out; int ldout;
};

template<int BM, int BN>
__global__ __launch_bounds__(512) void k_gemm(GArgs g) {
  constexpr int MI = BM / 32;
  constexpr int NJ = BN / 64;
  constexpr int IA = (BM * 8) / 512;
  constexpr int IB = (BN * 8) / 512;
  __shared__ bf16_t smA[BM * 64];
  __shared__ bf16_t smB[BN * 64];
  const int tid = threadIdx.x;
  const int m0 = blockIdx.y * BM, n0 = blockIdx.x * BN;
  const int wv = tid >> 6, lane = tid & 63;
  const int wm = wv >> 2, wn = wv & 3;
  const int lr = lane & 15, g4 = lane >> 4;

  f32x4 acc[MI][NJ];
#pragma unroll
  for (int i = 0; i < MI; i++)
#pragma unroll
    for (int j = 0; j < NJ; j++) acc[i][j] = f32x4{0.f, 0.f, 0.f, 0.f};

  for (int ps = 0; ps < g.np; ps++) {
    const bf16_t* A = g.p[ps].A;
    const bf16_t* Bt = g.p[ps].Bt;
    const int K = g.p[ps].K, lda = g.p[ps].lda, ldbt = g.p[ps].ldbt;
    for (int k0 = 0; k0 < K; k0 += 64) {
      bf16x8 ar[IA], br[IB];
#pragma unroll
      for (int r = 0; r < IA; r++) {
        int task = tid + r * 512, row = task >> 3, t = task & 7, sf = t ^ (row & 7);
        ar[r] = *(const bf16x8*)(A + (size_t)(m0 + row) * lda + k0 + sf * 8);
      }
#pragma unroll
      for (int r = 0; r < IB; r++) {
        int task = tid + r * 512, row = task >> 3, t = task & 7, sf = t ^ (row & 7);
        br[r] = *(const bf16x8*)(Bt + (size_t)(n0 + row) * ldbt + k0 + sf * 8);
      }
      __syncthreads();
#pragma unroll
      for (int r = 0; r < IA; r++) {
        int task = tid + r * 512, row = task >> 3, t = task & 7;
        *(bf16x8*)(smA + row * 64 + t * 8) = ar[r];
      }
#pragma unroll
      for (int r = 0; r < IB; r++) {
        int task = tid + r * 512, row = task >> 3, t = task & 7;
        *(bf16x8*)(smB + row * 64 + t * 8) = br[r];
      }
      __syncthreads();
#pragma unroll
      for (int ks = 0; ks < 2; ks++) {
        bf16x8 af[MI], bfr[NJ];
#pragma unroll
        for (int i = 0; i < MI; i++) {
          int row = wm * (BM / 2) + i * 16 + lr;
          af[i] = *(const bf16x8*)(smA + row * 64 + ((ks * 4 + g4) ^ (lr & 7)) * 8);
        }
#pragma unroll
        for (int j = 0; j < NJ; j++) {
          int row = wn * (BN / 4) + j * 16 + lr;
          bfr[j] = *(const bf16x8*)(smB + row * 64 + ((ks * 4 + g4) ^ (lr & 7)) * 8);
        }
#pragma unroll
        for (int i = 0; i < MI; i++)
#pragma unroll
          for (int j = 0; j < NJ; j++)
            acc[i][j] = __builtin_amdgcn_mfma_f32_16x16x32_bf16(af[i], bfr[j], acc[i][j], 0, 0, 0);
      }
    }
  }
#pragma unroll
  for (int i = 0; i < MI; i++)
#pragma unroll
    for (int j = 0; j < NJ; j++) {
      int col = n0 + wn * (BN / 4) + j * 16 + lr;
      float bb = g.bias ? g.bias[col] : 0.f;
#pragma unroll
      for (int r = 0; r < 4; r++) {
        int row = m0 + wm * (BM / 2) + i * 16 + (lane >> 4) * 4 + r;
        float v = acc[i][j][r] + bb;
        if (g.act == 1) v = sigm(v);
        g.out[(size_t)row * g.ldout + col] = v;
      }
    }
}

// ---------------- fused gates GEMM + cell state (swizzled LDS) ----------------
struct GatesArgs {
  const bf16_t* xhi; const bf16_t* h0b; const bf16_t* kt; const bf16_t* rkt;
  const float* bias; const float* c0; float* c_out; float* tc;
};

__global__ __launch_bounds__(512, 2) void k_gates(GatesArgs ga) {
  __shared__ bf16_t smA[64 * 64];
  __shared__ bf16_t smB[3 * 128 * 64];
  const int tid = threadIdx.x;
  const int n0 = blockIdx.x * 128;
  const int m0 = blockIdx.y * 64;
  const int wv = tid >> 6, lane = tid & 63;
  const int wm = wv >> 2, wn = wv & 3;
  const int lr = lane & 15, g4 = lane >> 4;

  f32x4 acc[3][2][2];
#pragma unroll
  for (int t = 0; t < 3; t++)
#pragma unroll
    for (int i = 0; i < 2; i++)
#pragma unroll
      for (int j = 0; j < 2; j++) acc[t][i][j] = f32x4{0.f, 0.f, 0.f, 0.f};

  for (int ps = 0; ps < 2; ps++) {
    const bf16_t* A  = ps ? ga.h0b : ga.xhi;
    const bf16_t* Bt = ps ? ga.rkt : ga.kt;
    const int K = ps ? 512 : 256, ld = K;
    for (int k0 = 0; k0 < K; k0 += 64) {
      int arow = tid >> 3, at = tid & 7, asf = at ^ (arow & 7);
      bf16x8 ar = *(const bf16x8*)(A + (size_t)(m0 + arow) * ld + k0 + asf * 8);
      bf16x8 br[6];
#pragma unroll
      for (int r = 0; r < 6; r++) {
        int task = tid + r * 512;
        int gate = task >> 10, rem = task & 1023, o = rem >> 3, t = rem & 7, sf = t ^ (o & 7);
        br[r] = *(const bf16x8*)(Bt + (size_t)(gate * 512 + n0 + o) * ld + k0 + sf * 8);
      }
      __syncthreads();
      *(bf16x8*)(smA + arow * 64 + at * 8) = ar;
#pragma unroll
      for (int r = 0; r < 6; r++) {
        int task = tid + r * 512;
        int gate = task >> 10, rem = task & 1023, o = rem >> 3, t = rem & 7;
        *(bf16x8*)(smB + (gate * 128 + o) * 64 + t * 8) = br[r];
      }
      __syncthreads();
#pragma unroll
      for (int ks = 0; ks < 2; ks++) {
        bf16x8 af[2];
#pragma unroll
        for (int i = 0; i < 2; i++) {
          int row = wm * 32 + i * 16 + lr;
          af[i] = *(const bf16x8*)(smA + row * 64 + ((ks * 4 + g4) ^ (lr & 7)) * 8);
        }
#pragma unroll
        for (int t = 0; t < 3; t++) {
          bf16x8 bfr[2];
#pragma unroll
          for (int j = 0; j < 2; j++) {
            int row = wn * 32 + j * 16 + lr;
            bfr[j] = *(const bf16x8*)(smB + (t * 128 + row) * 64 + ((ks * 4 + g4) ^ (lr & 7)) * 8);
          }
#pragma unroll
          for (int i = 0; i < 2; i++)
#pragma unroll
            for (int j = 0; j < 2; j++)
              acc[t][i][j] = __builtin_amdgcn_mfma_f32_16x16x32_bf16(af[i], bfr[j], acc[t][i][j], 0, 0, 0);
        }
      }
    }
  }
#pragma unroll
  for (int i = 0; i < 2; i++)
#pragma unroll
    for (int j = 0; j < 2; j++) {
      int col = n0 + wn * 32 + j * 16 + lr;
      float bi = ga.bias[col], bf_ = ga.bias[512 + col], bc = ga.bias[1024 + col];
#pragma unroll
      for (int r = 0; r < 4; r++) {
        int row = m0 + wm * 32 + i * 16 + (lane >> 4) * 4 + r;
        size_t idx = (size_t)row * 512 + col;
        float iv = sigm(acc[0][i][j][r] + bi);
        float fv = sigm(acc[1][i][j][r] + bf_);
        float cc = sigm(acc[2][i][j][r] + bc);
        float cv = fv * ga.c0[idx] + iv * fast_tanh(cc);
        ga.c_out[idx] = cv;
        ga.tc[idx] = fast_tanh(cv);
      }
    }
}

// ---------------- Fourier-KAN GEMM v9: fine-grain blocks ----------------
// BM=64, BN=128, q=8 K-split, grid 1024 = 4 blocks/CU. 128 thr = 2 waves
// (wave-tile 64x64, acc[4][4]). B-fragments: coalesced reg loads from fcb2
// (named dbuf banks, compiler-counted waits); A: shared trig-gen into
// swizzled LDS dbuf. One lgkm-only barrier/iter, syncs just 2 waves; 4
// independent blocks/CU overlap stalls. LDS 24.8KB.
struct FArgs { const float* agg; const bf16_t* fcb2; float* P[8]; };

__global__ __launch_bounds__(128, 2) void k_fourier(FArgs fa) {
  __shared__ float  zl[64 * 33];        // 8.4 KB
  __shared__ bf16_t Asm[2][64 * 64];    // 16 KB
  const int tid = threadIdx.x;
  const int bx = blockIdx.x;            // 1024 blocks; q = bx&7 = XCD id
  const int q = bx & 7, nb = (bx >> 3) & 1, mb = bx >> 4;
  const int m0 = mb * 64, n0 = nb * 128, i0 = q * 32;
  const int wv = tid >> 6, lane = tid & 63;
  const int wn = wv;                    // 2 waves, both cover all 64 rows
  const int lr = lane & 15, g4 = lane >> 4;

  // stage z tile [64 rows x 32 i] -> zl (stride 33)
#pragma unroll
  for (int r = 0; r < 4; r++) {
    int task = tid + r * 128, row = task >> 3, seg = task & 7;
    float4 v = *(const float4*)(fa.agg + (size_t)(m0 + row) * 256 + i0 + seg * 4);
    zl[row * 33 + seg * 4 + 0] = v.x;
    zl[row * 33 + seg * 4 + 1] = v.y;
    zl[row * 33 + seg * 4 + 2] = v.z;
    zl[row * 33 + seg * 4 + 3] = v.w;
  }

  // B: coalesced 16B/lane loads from fcb2.
  // strides: i 16384, nb 8192, wn 4096, j 1024, ks 512, lane*8.
  const bf16_t* pB = fa.fcb2 + (size_t)i0 * 16384 + nb * 8192 + wn * 4096 + lane * 8;
  auto loadB = [&](int i, bf16x8 (&b)[8]) {
#pragma unroll
    for (int ks = 0; ks < 2; ks++)
#pragma unroll
      for (int j = 0; j < 4; j++)
        b[ks * 4 + j] = *(const bf16x8*)(pB + (size_t)i * 16384 + j * 1024 + ks * 512);
  };

  // A trig-gen (shared): row=tid>>1 (0..63), hp=tid&1 -> g4 in {2hp,2hp+1}.
  const int grow = tid >> 1, hp = tid & 1;
  const float* zp = zl + grow * 33;
  const int as0 = grow * 64 + (((2 * hp    ) ^ (grow & 7)) * 8);
  const int as1 = grow * 64 + (((2 * hp + 1) ^ (grow & 7)) * 8);
  const int as2 = grow * 64 + (((4 + 2 * hp) ^ (grow & 7)) * 8);
  const int as3 = grow * 64 + (((5 + 2 * hp) ^ (grow & 7)) * 8);
  auto genA = [&](int i, bf16_t* Ab) {
    float zr = zp[i];
    bf16x8 c0v, c1v, s0v, s1v;
#pragma unroll
    for (int t = 0; t < 8; t++) {
      float r0 = fract_f(zr * (float)(hp * 16 + t + 1));
      float r1 = fract_f(zr * (float)(hp * 16 + 8 + t + 1));
      c0v[t] = (bf16_t)cos_rev(r0); s0v[t] = (bf16_t)sin_rev(r0);
      c1v[t] = (bf16_t)cos_rev(r1); s1v[t] = (bf16_t)sin_rev(r1);
    }
    *(bf16x8*)(Ab + as0) = c0v;
    *(bf16x8*)(Ab + as1) = c1v;
    *(bf16x8*)(Ab + as2) = s0v;
    *(bf16x8*)(Ab + as3) = s1v;
  };

  // fixed A-fragment LDS offsets (rows 0..63)
  int offA[8];
#pragma unroll
  for (int ks = 0; ks < 2; ks++)
#pragma unroll
    for (int i4 = 0; i4 < 4; i4++)
      offA[ks * 4 + i4] = (i4 * 16 + lr) * 64 + ((ks * 4 + g4) ^ (lr & 7)) * 8;

  f32x4 acc[4][4];
#pragma unroll
  for (int i = 0; i < 4; i++)
#pragma unroll
    for (int j = 0; j < 4; j++) acc[i][j] = f32x4{0.f, 0.f, 0.f, 0.f};

  auto domfma = [&](const bf16x8 (&af)[8], const bf16x8 (&b)[8]) {
    __builtin_amdgcn_s_setprio(1);
#pragma unroll
    for (int ks = 0; ks < 2; ks++)
#pragma unroll
      for (int i4 = 0; i4 < 4; i4++)
#pragma unroll
        for (int j = 0; j < 4; j++)
          acc[i4][j] = __builtin_amdgcn_mfma_f32_16x16x32_bf16(af[ks * 4 + i4], b[ks * 4 + j], acc[i4][j], 0, 0, 0);
    __builtin_amdgcn_s_setprio(0);
  };
  auto readA = [&](const bf16_t* Ac, bf16x8 (&af)[8]) {
#pragma unroll
    for (int t = 0; t < 8; t++) af[t] = *(const bf16x8*)(Ac + offA[t]);
  };

  bf16x8 bA_[8], bB_[8];
  __syncthreads();                      // zl visible
  loadB(0, bA_);
  genA(0, Asm[0]);
  asm volatile("s_waitcnt lgkmcnt(0)" ::: "memory");
  __builtin_amdgcn_s_barrier();

#pragma unroll 1
  for (int it = 0; it < 16; it++) {
    const int i = it * 2;
    bf16x8 af[8];
    if (i < 31) loadB(i + 1, bB_);
    readA(Asm[0], af);
    if (i < 31) genA(i + 1, Asm[1]);
    domfma(af, bA_);
    asm volatile("s_waitcnt lgkmcnt(0)" ::: "memory");
    __builtin_amdgcn_s_barrier();
    if (i + 2 < 32) loadB(i + 2, bA_);
    readA(Asm[1], af);
    if (i + 2 < 32) genA(i + 2, Asm[0]);
    domfma(af, bB_);
    asm volatile("s_waitcnt lgkmcnt(0)" ::: "memory");
    __builtin_amdgcn_s_barrier();
  }

  float* outp = fa.P[q];
#pragma unroll
  for (int i = 0; i < 4; i++)
#pragma unroll
    for (int j = 0; j < 4; j++) {
      int col = n0 + wn * 64 + j * 16 + lr;
#pragma unroll
      for (int r = 0; r < 4; r++) {
        int row = m0 + i * 16 + g4 * 4 + r;
        outp[(size_t)row * 256 + col] = acc[i][j][r];
      }
    }
}

// ---------------- reduce 8 K-split partials + new_s epilogue (float4) -------
struct RArgs {
  const float* P[8];
  const float* fb; const float* tk; const float* s0;
  float* news; bf16_t* sob;
};

__global__ __launch_bounds__(256) void k_freduce(RArgs ra) {
  int stride = gridDim.x * blockDim.x;
  for (int qd = blockIdx.x * blockDim.x + threadIdx.x; qd < 262144; qd += stride) {
    int i = qd * 4, o = i & 255;
    float4 v = *(const float4*)(ra.P[0] + i);
#pragma unroll
    for (int c = 1; c < 8; c++) {
      float4 p = *(const float4*)(ra.P[c] + i);
      v.x += p.x; v.y += p.y; v.z += p.z; v.w += p.w;
    }
    v.x += ra.fb[o + 0]; v.y += ra.fb[o + 1]; v.z += ra.fb[o + 2]; v.w += ra.fb[o + 3];
    bf16x4 sb; sb[0] = (bf16_t)v.x; sb[1] = (bf16_t)v.y; sb[2] = (bf16_t)v.z; sb[3] = (bf16_t)v.w;
    *(bf16x4*)(ra.sob + i) = sb;
    float4 s = *(const float4*)(ra.s0 + i);
    float4 ns;
    ns.x = ra.tk[o + 0] * v.x + ra.tk[256 + o + 0] * s.x;
    ns.y = ra.tk[o + 1] * v.y + ra.tk[256 + o + 1] * s.y;
    ns.z = ra.tk[o + 2] * v.z + ra.tk[256 + o + 2] * s.z;
    ns.w = ra.tk[o + 3] * v.w + ra.tk[256 + o + 3] * s.w;
    *(float4*)(ra.news + i) = ns;
  }
}

// ---------------- fused out-proj GEMM + LayerNorm ----------------
// BM=64, BN=512 (full row), K=256, 512 thr 8 waves 2m x 4n (wave-tile
// 32x128, acc[2][8]). Epilogue: o=sigm(acc+ab), h0=o*tc, row-512 LN via
// lr-butterfly + cross-wave LDS reduce, writes h directly. grid 64.
struct OLArgs {
  const bf16_t* sob; const bf16_t* awt; const float* ab;
  const float* tc; const float* lg; const float* lb;
  float* h;
};

__global__ __launch_bounds__(512) void k_oln(OLArgs a) {
  __shared__ bf16_t smA[64 * 64];
  __shared__ bf16_t smB[512 * 64];
  __shared__ float redS[64][4], redSS[64][4];
  const int tid = threadIdx.x;
  const int m0 = blockIdx.x * 64;
  const int wv = tid >> 6, lane = tid & 63;
  const int wm = wv >> 2, wn = wv & 3;
  const int lr = lane & 15, g4 = lane >> 4;

  f32x4 acc[2][8];
#pragma unroll
  for (int i = 0; i < 2; i++)
#pragma unroll
    for (int j = 0; j < 8; j++) acc[i][j] = f32x4{0.f, 0.f, 0.f, 0.f};

  for (int k0 = 0; k0 < 256; k0 += 64) {
    // A: 1 task/thread; B: 8 tasks/thread
    int arow = tid >> 3, at = tid & 7, asf = at ^ (arow & 7);
    bf16x8 ar = *(const bf16x8*)(a.sob + (size_t)(m0 + arow) * 256 + k0 + asf * 8);
    bf16x8 br[8];
#pragma unroll
    for (int r = 0; r < 8; r++) {
      int task = tid + r * 512, row = task >> 3, t = task & 7, sf = t ^ (row & 7);
      br[r] = *(const bf16x8*)(a.awt + (size_t)row * 256 + k0 + sf * 8);
    }
    __syncthreads();
    *(bf16x8*)(smA + arow * 64 + at * 8) = ar;
#pragma unroll
    for (int r = 0; r < 8; r++) {
      int task = tid + r * 512, row = task >> 3, t = task & 7;
      *(bf16x8*)(smB + row * 64 + t * 8) = br[r];
    }
    __syncthreads();
#pragma unroll
    for (int ks = 0; ks < 2; ks++) {
      bf16x8 af[2], bfr[8];
#pragma unroll
      for (int i = 0; i < 2; i++) {
        int row = wm * 32 + i * 16 + lr;
        af[i] = *(const bf16x8*)(smA + row * 64 + ((ks * 4 + g4) ^ (lr & 7)) * 8);
      }
#pragma unroll
      for (int j = 0; j < 8; j++) {
        int row = wn * 128 + j * 16 + lr;
        bfr[j] = *(const bf16x8*)(smB + row * 64 + ((ks * 4 + g4) ^ (lr & 7)) * 8);
      }
#pragma unroll
      for (int i = 0; i < 2; i++)
#pragma unroll
        for (int j = 0; j < 8; j++)
          acc[i][j] = __builtin_amdgcn_mfma_f32_16x16x32_bf16(af[i], bfr[j], acc[i][j], 0, 0, 0);
    }
  }

  // epilogue: sigmoid + *tc, then LN over the 512-wide row
#pragma unroll
  for (int i = 0; i < 2; i++) {
#pragma unroll
    for (int r = 0; r < 4; r++) {
      int rowL = wm * 32 + i * 16 + g4 * 4 + r;
      int row = m0 + rowL;
      float s = 0.f, ss = 0.f;
#pragma unroll
      for (int j = 0; j < 8; j++) {
        int col = wn * 128 + j * 16 + lr;
        float ov = sigm(acc[i][j][r] + a.ab[col]);
        float hv = ov * a.tc[(size_t)row * 512 + col];
        acc[i][j][r] = hv;
        s += hv; ss += hv * hv;
      }
#pragma unroll
      for (int off = 1; off < 16; off <<= 1) {
        s += __shfl_xor(s, off);
        ss += __shfl_xor(ss, off);
      }
      if (lr == 0) { redS[rowL][wn] = s; redSS[rowL][wn] = ss; }
    }
  }
  __syncthreads();
#pragma unroll
  for (int i = 0; i < 2; i++)
#pragma unroll
    for (int r = 0; r < 4; r++) {
      int rowL = wm * 32 + i * 16 + g4 * 4 + r;
      int row = m0 + rowL;
      float S  = redS[rowL][0] + redS[rowL][1] + redS[rowL][2] + redS[rowL][3];
      float SS = redSS[rowL][0] + redSS[rowL][1] + redSS[rowL][2] + redSS[rowL][3];
      float mu = S * (1.f / 512.f);
      float var = SS * (1.f / 512.f) - mu * mu;
      float rs = rsqrtf(var + 1e-5f);
#pragma unroll
      for (int j = 0; j < 8; j++) {
        int col = wn * 128 + j * 16 + lr;
        a.h[(size_t)row * 512 + col] = (acc[i][j][r] - mu) * rs * a.lg[col] + a.lb[col];
      }
    }
}

// ---------------- launcher ----------------
extern "C" void kernel_launch(void* const* d_in, const int* in_sizes, int n_in,
                              void* d_out, int out_size, void* d_ws, size_t ws_size,
                              hipStream_t stream) {
  const float* x    = (const float*)d_in[0];
  const float* h0   = (const float*)d_in[1];
  const float* c0   = (const float*)d_in[2];
  const float* s0   = (const float*)d_in[3];
  const float* Wk   = (const float*)d_in[4];
  const float* Wr   = (const float*)d_in[5];
  const float* bias = (const float*)d_in[6];
  const float* kx   = (const float*)d_in[7];
  const float* kh   = (const float*)d_in[8];
  const float* tk   = (const float*)d_in[9];
  const float* fc   = (const float*)d_in[10];
  const float* fb   = (const float*)d_in[11];
  const float* aw   = (const float*)d_in[12];
  const float* ab   = (const float*)d_in[13];
  const float* lg   = (const float*)d_in[14];
  const float* lbp  = (const float*)d_in[15];
  float* out = (float*)d_out;
  char* ws = (char*)d_ws;
  auto BF = [&](unsigned long long off) { return (bf16_t*)(ws + off); };
  auto FP = [&](unsigned long long off) { return (float*)(ws + off); };

  // fused conversions + fcb2 tiling + transposes
  k_prep<<<3456, 256, 0, stream>>>(x, h0, s0, fc, Wk, Wr, aw, kx, kh,
                                   BF(O_XHI), BF(O_XLO), BF(O_H0),
                                   BF(O_S0H), BF(O_S0L), BF(O_FCB),
                                   BF(O_KT), BF(O_RKT), BF(O_AWT),
                                   BF(O_KXH), BF(O_KXL), BF(O_KHH), BF(O_KHL));

  // fused gates GEMM + cell: c -> d_out[2M..4M), tanh(c) -> TC
  {
    GatesArgs ga{ BF(O_XHI), BF(O_H0), BF(O_KT), BF(O_RKT), bias, c0,
                  out + 2097152, FP(O_TC) };
    k_gates<<<dim3(4, 64), 512, 0, stream>>>(ga);
  }

  // agg GEMM (hi/lo split), output in revolutions
  {
    GArgs g{};
    g.p[0] = { BF(O_XHI), BF(O_KXH), 256, 256, 256 };
    g.p[1] = { BF(O_XHI), BF(O_KXL), 256, 256, 256 };
    g.p[2] = { BF(O_XLO), BF(O_KXH), 256, 256, 256 };
    g.p[3] = { BF(O_S0H), BF(O_KHH), 256, 256, 256 };
    g.p[4] = { BF(O_S0H), BF(O_KHL), 256, 256, 256 };
    g.p[5] = { BF(O_S0L), BF(O_KHH), 256, 256, 256 };
    g.np = 6; g.bias = nullptr; g.act = 0;
    g.out = FP(O_AGG); g.ldout = 256;
    k_gemm<64, 64><<<dim3(4, 64), 512, 0, stream>>>(g);
  }

  // Fourier KAN (q=8 K-split, 1024 blocks = 4/CU). P chunks 0-2 overlay
  // XHI/XLO, H0, S0H/S0L (dead after agg GEMM above).
  FArgs fa;
  fa.agg = FP(O_AGG); fa.fcb2 = BF(O_FCB);
  fa.P[0] = FP(0ull);
  fa.P[1] = FP(4194304ull);
  fa.P[2] = FP(8388608ull);
  for (int c = 3; c < 8; c++) fa.P[c] = FP(O_P3 + (unsigned long long)(c - 3) * 4194304ull);
  k_fourier<<<1024, 128, 0, stream>>>(fa);

  // reduce partials, emit new_s (d_out[4M..5M)) + sub_out bf16
  RArgs ra;
  for (int c = 0; c < 8; c++) ra.P[c] = fa.P[c];
  ra.fb = fb; ra.tk = tk; ra.s0 = s0;
  ra.news = out + 4194304; ra.sob = BF(O_SOB);
  k_freduce<<<1024, 256, 0, stream>>>(ra);

  // fused out-proj + LayerNorm -> h in d_out[0..2M)
  {
    OLArgs oa{ BF(O_SOB), BF(O_AWT), ab, FP(O_TC), lg, lbp, out };
    k_oln<<<64, 512, 0, stream>>>(oa);
  }
}

// Round 13
// 120.665 us; speedup vs baseline: 1.0276x; 1.0276x over previous
//
#include <hip/hip_runtime.h>
#include <hip/hip_bf16.h>

typedef __bf16 bf16_t;
typedef __bf16 bf16x4 __attribute__((ext_vector_type(4)));
typedef __bf16 bf16x8 __attribute__((ext_vector_type(8)));
typedef float  f32x4  __attribute__((ext_vector_type(4)));

#define NB 4096
#define IN_DIM 256
#define HID 512
#define SUB 256
#define GRID_ 32

// ---------------- math helpers ----------------
__device__ __forceinline__ float fract_f(float x) {
#if __has_builtin(__builtin_amdgcn_fractf)
  return __builtin_amdgcn_fractf(x);
#else
  return x - floorf(x);
#endif
}
__device__ __forceinline__ float cos_rev(float rev) {
#if __has_builtin(__builtin_amdgcn_cosf)
  return __builtin_amdgcn_cosf(rev);
#else
  return __cosf(rev * 6.283185307179586f);
#endif
}
__device__ __forceinline__ float sin_rev(float rev) {
#if __has_builtin(__builtin_amdgcn_sinf)
  return __builtin_amdgcn_sinf(rev);
#else
  return __sinf(rev * 6.283185307179586f);
#endif
}
__device__ __forceinline__ float sigm(float v) { return 1.f / (1.f + __expf(-v)); }
__device__ __forceinline__ float fast_tanh(float x) {
  float e = __expf(2.f * x);
  return (e - 1.f) / (e + 1.f);
}
#define INV2PI 0.15915494309189535f

// ---------------- workspace layout (bytes), high-water 59.77MB ----------------
#define O_XHI   0ull
#define O_XLO   2097152ull
#define O_H0    4194304ull
#define O_S0H   8388608ull
#define O_S0L   10485760ull
#define O_FCB   12582912ull   // fcb2 tiled layout, 8.4MB
#define O_O     12582912ull   // overlays FCB (fcb2 dead after k_fourier)
#define O_KT    20971520ull
#define O_RKT   21757952ull
#define O_AWT   23330816ull
#define O_KXH   23592960ull
#define O_KXL   23724032ull
#define O_KHH   23855104ull
#define O_KHL   23986176ull
#define O_TC    24117248ull
#define O_SOB   32505856ull
#define O_AGG   34603008ull
#define O_P3    38797312ull   // chunks 3..7, 5 x 4MB -> end 59768832

// ---------------- transpose-convert body ----------------
__device__ __forceinline__ void tconv_body(const float* __restrict__ src,
                                           bf16_t* __restrict__ hi,
                                           bf16_t* __restrict__ lo,
                                           int R, int C, int bx, int by,
                                           bool wantlo, float scale) {
  __shared__ float t[32][33];
  int c0 = bx * 32, r0 = by * 32;
  int tx = threadIdx.x & 31, ty = threadIdx.x >> 5;
#pragma unroll
  for (int rr = 0; rr < 4; rr++) {
    int r = ty + rr * 8;
    t[r][tx] = src[(size_t)(r0 + r) * C + c0 + tx];
  }
  __syncthreads();
#pragma unroll
  for (int rr = 0; rr < 4; rr++) {
    int cl = ty + rr * 8;
    float f = t[tx][cl] * scale;
    bf16_t h = (bf16_t)f;
    size_t oi = (size_t)(c0 + cl) * R + r0 + tx;
    hi[oi] = h;
    if (wantlo) lo[oi] = (bf16_t)(f - (float)h);
  }
}

// ---------------- fused prep (conversions + fcb2 tiling) + all transposes ----
__global__ __launch_bounds__(256) void k_prep(const float* __restrict__ x,
                                              const float* __restrict__ h0,
                                              const float* __restrict__ s0,
                                              const float* __restrict__ fc,
                                              const float* __restrict__ Wk,
                                              const float* __restrict__ Wr,
                                              const float* __restrict__ aw,
                                              const float* __restrict__ kx,
                                              const float* __restrict__ kh,
                                              bf16_t* __restrict__ xhi, bf16_t* __restrict__ xlo,
                                              bf16_t* __restrict__ h0b,
                                              bf16_t* __restrict__ s0h, bf16_t* __restrict__ s0l,
                                              bf16_t* __restrict__ fcb2,
                                              bf16_t* __restrict__ kt,
                                              bf16_t* __restrict__ rkt,
                                              bf16_t* __restrict__ awt,
                                              bf16_t* __restrict__ kxh, bf16_t* __restrict__ kxl,
                                              bf16_t* __restrict__ khh, bf16_t* __restrict__ khl) {
  int bid = blockIdx.x;
  if (bid < 2048) {
    for (int q = bid * 256 + threadIdx.x; q < 2097152; q += 524288) {
      if (q < 1048576) {
        const float* src; bf16_t* hi; bf16_t* lo = nullptr; int base;
        if (q < 262144)       { src = x;  hi = xhi; lo = xlo; base = q; }
        else if (q < 786432)  { src = h0; hi = h0b;           base = q - 262144; }
        else                  { src = s0; hi = s0h; lo = s0l; base = q - 786432; }
        float4 v = *(const float4*)(src + (size_t)base * 4);
        bf16x4 h; h[0] = (bf16_t)v.x; h[1] = (bf16_t)v.y; h[2] = (bf16_t)v.z; h[3] = (bf16_t)v.w;
        *(bf16x4*)(hi + (size_t)base * 4) = h;
        if (lo) {
          bf16x4 l;
          l[0] = (bf16_t)(v.x - (float)h[0]); l[1] = (bf16_t)(v.y - (float)h[1]);
          l[2] = (bf16_t)(v.z - (float)h[2]); l[3] = (bf16_t)(v.w - (float)h[3]);
          *(bf16x4*)(lo + (size_t)base * 4) = l;
        }
      } else {
        int f = q - 1048576;              // fc quad
        int e = f * 4;
        int g = e & 31, i = (e >> 5) & 255, o = (e >> 13) & 255, s = e >> 21;
        float4 v = *(const float4*)(fc + (size_t)e);
        bf16x4 h; h[0] = (bf16_t)v.x; h[1] = (bf16_t)v.y; h[2] = (bf16_t)v.z; h[3] = (bf16_t)v.w;
        int nb = o >> 7, wn = (o >> 6) & 1, j = (o >> 4) & 3, lr = o & 15;
        int g4 = g >> 3, t0 = g & 7;
        size_t idx = ((((((size_t)(i * 2 + nb) * 2 + wn) * 4 + j) * 2 + s) * 4 + g4) * 16 + lr) * 8 + t0;
        *(bf16x4*)(fcb2 + idx) = h;
      }
    }
  } else {
    int b = bid - 2048;
    if (b < 384)       { tconv_body(Wk, kt,  nullptr, 256, 1536, b % 48, b / 48, false, 1.f); }
    else if (b < 1152) { b -= 384;  tconv_body(Wr, rkt, nullptr, 512, 1536, b % 48, b / 48, false, 1.f); }
    else if (b < 1280) { b -= 1152; tconv_body(aw, awt, nullptr, 256, 512,  b % 16, b / 16, false, 1.f); }
    else if (b < 1344) { b -= 1280; tconv_body(kx, kxh, kxl,     256, 256,  b % 8,  b / 8,  true, INV2PI); }
    else               { b -= 1344; tconv_body(kh, khh, khl,     256, 256,  b % 8,  b / 8,  true, INV2PI); }
  }
}

// ---------------- generic multi-pass bf16 MFMA GEMM (stride 64 + XOR swz) ---
struct Pass { const bf16_t* A; const bf16_t* Bt; int K; int lda; int ldbt; };
struct GArgs {
  Pass p[6]; int np;
  const float* bias;
  int act;
  float* out; int ldout;
};

template<int BM, int BN>
__global__ __launch_bounds__(512) void k_gemm(GArgs g) {
  constexpr int MI = BM / 32;
  constexpr int NJ = BN / 64;
  constexpr int IA = (BM * 8) / 512;
  constexpr int IB = (BN * 8) / 512;
  __shared__ bf16_t smA[BM * 64];
  __shared__ bf16_t smB[BN * 64];
  const int tid = threadIdx.x;
  const int m0 = blockIdx.y * BM, n0 = blockIdx.x * BN;
  const int wv = tid >> 6, lane = tid & 63;
  const int wm = wv >> 2, wn = wv & 3;
  const int lr = lane & 15, g4 = lane >> 4;

  f32x4 acc[MI][NJ];
#pragma unroll
  for (int i = 0; i < MI; i++)
#pragma unroll
    for (int j = 0; j < NJ; j++) acc[i][j] = f32x4{0.f, 0.f, 0.f, 0.f};

  for (int ps = 0; ps < g.np; ps++) {
    const bf16_t* A = g.p[ps].A;
    const bf16_t* Bt = g.p[ps].Bt;
    const int K = g.p[ps].K, lda = g.p[ps].lda, ldbt = g.p[ps].ldbt;
    for (int k0 = 0; k0 < K; k0 += 64) {
      bf16x8 ar[IA], br[IB];
#pragma unroll
      for (int r = 0; r < IA; r++) {
        int task = tid + r * 512, row = task >> 3, t = task & 7, sf = t ^ (row & 7);
        ar[r] = *(const bf16x8*)(A + (size_t)(m0 + row) * lda + k0 + sf * 8);
      }
#pragma unroll
      for (int r = 0; r < IB; r++) {
        int task = tid + r * 512, row = task >> 3, t = task & 7, sf = t ^ (row & 7);
        br[r] = *(const bf16x8*)(Bt + (size_t)(n0 + row) * ldbt + k0 + sf * 8);
      }
      __syncthreads();
#pragma unroll
      for (int r = 0; r < IA; r++) {
        int task = tid + r * 512, row = task >> 3, t = task & 7;
        *(bf16x8*)(smA + row * 64 + t * 8) = ar[r];
      }
#pragma unroll
      for (int r = 0; r < IB; r++) {
        int task = tid + r * 512, row = task >> 3, t = task & 7;
        *(bf16x8*)(smB + row * 64 + t * 8) = br[r];
      }
      __syncthreads();
#pragma unroll
      for (int ks = 0; ks < 2; ks++) {
        bf16x8 af[MI], bfr[NJ];
#pragma unroll
        for (int i = 0; i < MI; i++) {
          int row = wm * (BM / 2) + i * 16 + lr;
          af[i] = *(const bf16x8*)(smA + row * 64 + ((ks * 4 + g4) ^ (lr & 7)) * 8);
        }
#pragma unroll
        for (int j = 0; j < NJ; j++) {
          int row = wn * (BN / 4) + j * 16 + lr;
          bfr[j] = *(const bf16x8*)(smB + row * 64 + ((ks * 4 + g4) ^ (lr & 7)) * 8);
        }
#pragma unroll
        for (int i = 0; i < MI; i++)
#pragma unroll
          for (int j = 0; j < NJ; j++)
            acc[i][j] = __builtin_amdgcn_mfma_f32_16x16x32_bf16(af[i], bfr[j], acc[i][j], 0, 0, 0);
      }
    }
  }
#pragma unroll
  for (int i = 0; i < MI; i++)
#pragma unroll
    for (int j = 0; j < NJ; j++) {
      int col = n0 + wn * (BN / 4) + j * 16 + lr;
      float bb = g.bias ? g.bias[col] : 0.f;
#pragma unroll
      for (int r = 0; r < 4; r++) {
        int row = m0 + wm * (BM / 2) + i * 16 + (lane >> 4) * 4 + r;
        float v = acc[i][j][r] + bb;
        if (g.act == 1) v = sigm(v);
        g.out[(size_t)row * g.ldout + col] = v;
      }
    }
}

// ---------------- fused gates GEMM + cell state (swizzled LDS) ----------------
struct GatesArgs {
  const bf16_t* xhi; const bf16_t* h0b; const bf16_t* kt; const bf16_t* rkt;
  const float* bias; const float* c0; float* c_out; float* tc;
};

__global__ __launch_bounds__(512, 2) void k_gates(GatesArgs ga) {
  __shared__ bf16_t smA[64 * 64];
  __shared__ bf16_t smB[3 * 128 * 64];
  const int tid = threadIdx.x;
  const int n0 = blockIdx.x * 128;
  const int m0 = blockIdx.y * 64;
  const int wv = tid >> 6, lane = tid & 63;
  const int wm = wv >> 2, wn = wv & 3;
  const int lr = lane & 15, g4 = lane >> 4;

  f32x4 acc[3][2][2];
#pragma unroll
  for (int t = 0; t < 3; t++)
#pragma unroll
    for (int i = 0; i < 2; i++)
#pragma unroll
      for (int j = 0; j < 2; j++) acc[t][i][j] = f32x4{0.f, 0.f, 0.f, 0.f};

  for (int ps = 0; ps < 2; ps++) {
    const bf16_t* A  = ps ? ga.h0b : ga.xhi;
    const bf16_t* Bt = ps ? ga.rkt : ga.kt;
    const int K = ps ? 512 : 256, ld = K;
    for (int k0 = 0; k0 < K; k0 += 64) {
      int arow = tid >> 3, at = tid & 7, asf = at ^ (arow & 7);
      bf16x8 ar = *(const bf16x8*)(A + (size_t)(m0 + arow) * ld + k0 + asf * 8);
      bf16x8 br[6];
#pragma unroll
      for (int r = 0; r < 6; r++) {
        int task = tid + r * 512;
        int gate = task >> 10, rem = task & 1023, o = rem >> 3, t = rem & 7, sf = t ^ (o & 7);
        br[r] = *(const bf16x8*)(Bt + (size_t)(gate * 512 + n0 + o) * ld + k0 + sf * 8);
      }
      __syncthreads();
      *(bf16x8*)(smA + arow * 64 + at * 8) = ar;
#pragma unroll
      for (int r = 0; r < 6; r++) {
        int task = tid + r * 512;
        int gate = task >> 10, rem = task & 1023, o = rem >> 3, t = rem & 7;
        *(bf16x8*)(smB + (gate * 128 + o) * 64 + t * 8) = br[r];
      }
      __syncthreads();
#pragma unroll
      for (int ks = 0; ks < 2; ks++) {
        bf16x8 af[2];
#pragma unroll
        for (int i = 0; i < 2; i++) {
          int row = wm * 32 + i * 16 + lr;
          af[i] = *(const bf16x8*)(smA + row * 64 + ((ks * 4 + g4) ^ (lr & 7)) * 8);
        }
#pragma unroll
        for (int t = 0; t < 3; t++) {
          bf16x8 bfr[2];
#pragma unroll
          for (int j = 0; j < 2; j++) {
            int row = wn * 32 + j * 16 + lr;
            bfr[j] = *(const bf16x8*)(smB + (t * 128 + row) * 64 + ((ks * 4 + g4) ^ (lr & 7)) * 8);
          }
#pragma unroll
          for (int i = 0; i < 2; i++)
#pragma unroll
            for (int j = 0; j < 2; j++)
              acc[t][i][j] = __builtin_amdgcn_mfma_f32_16x16x32_bf16(af[i], bfr[j], acc[t][i][j], 0, 0, 0);
        }
      }
    }
  }
#pragma unroll
  for (int i = 0; i < 2; i++)
#pragma unroll
    for (int j = 0; j < 2; j++) {
      int col = n0 + wn * 32 + j * 16 + lr;
      float bi = ga.bias[col], bf_ = ga.bias[512 + col], bc = ga.bias[1024 + col];
#pragma unroll
      for (int r = 0; r < 4; r++) {
        int row = m0 + wm * 32 + i * 16 + (lane >> 4) * 4 + r;
        size_t idx = (size_t)row * 512 + col;
        float iv = sigm(acc[0][i][j][r] + bi);
        float fv = sigm(acc[1][i][j][r] + bf_);
        float cc = sigm(acc[2][i][j][r] + bc);
        float cv = fv * ga.c0[idx] + iv * fast_tanh(cc);
        ga.c_out[idx] = cv;
        ga.tc[idx] = fast_tanh(cv);
      }
    }
}

// ---------------- Fourier-KAN GEMM v10: 4-wave blocks, 4 waves/SIMD ---------
// BM=64, BN=128, q=8 K-split, grid 1024 = 4 blocks/CU x 4 waves = 16 waves/CU.
// Waves 2m x 2n, wave-tile 32x64 (acc[2][4]). B: coalesced reg loads from
// fcb2 (named dbuf banks); A: shared trig-gen (16 trig/thread/iter) into
// swizzled LDS dbuf; one lgkm-only barrier/iter. LDS 24.8KB.
struct FArgs { const float* agg; const bf16_t* fcb2; float* P[8]; };

__global__ __launch_bounds__(256, 2) void k_fourier(FArgs fa) {
  __shared__ float  zl[64 * 33];        // 8.4 KB
  __shared__ bf16_t Asm[2][64 * 64];    // 16 KB
  const int tid = threadIdx.x;
  const int bx = blockIdx.x;            // 1024 blocks; q = bx&7 = XCD id
  const int q = bx & 7, nb = (bx >> 3) & 1, mb = bx >> 4;
  const int m0 = mb * 64, n0 = nb * 128, i0 = q * 32;
  const int wv = tid >> 6, lane = tid & 63;
  const int wm = wv >> 1, wn = wv & 1;
  const int lr = lane & 15, g4 = lane >> 4;

  // stage z tile [64 rows x 32 i] -> zl (stride 33)
#pragma unroll
  for (int r = 0; r < 2; r++) {
    int task = tid + r * 256, row = task >> 3, seg = task & 7;
    float4 v = *(const float4*)(fa.agg + (size_t)(m0 + row) * 256 + i0 + seg * 4);
    zl[row * 33 + seg * 4 + 0] = v.x;
    zl[row * 33 + seg * 4 + 1] = v.y;
    zl[row * 33 + seg * 4 + 2] = v.z;
    zl[row * 33 + seg * 4 + 3] = v.w;
  }

  // B: coalesced 16B/lane loads from fcb2 (strides: i 16384, nb 8192,
  // wn 4096, j 1024, ks 512, lane*8).
  const bf16_t* pB = fa.fcb2 + (size_t)i0 * 16384 + nb * 8192 + wn * 4096 + lane * 8;
  auto loadB = [&](int i, bf16x8 (&b)[8]) {
#pragma unroll
    for (int ks = 0; ks < 2; ks++)
#pragma unroll
      for (int j = 0; j < 4; j++)
        b[ks * 4 + j] = *(const bf16x8*)(pB + (size_t)i * 16384 + j * 1024 + ks * 512);
  };

  // A trig-gen (shared): row=tid>>2 (0..63), hq=tid&3 -> cos octet g4=hq,
  // sin octet g4=hq (slots 4..7). 16 trig/thread/iter.
  const int grow = tid >> 2, hq = tid & 3;
  const float* zp = zl + grow * 33;
  const int as0 = grow * 64 + ((hq       ^ (grow & 7)) * 8);
  const int as1 = grow * 64 + (((4 + hq) ^ (grow & 7)) * 8);
  auto genA = [&](int i, bf16_t* Ab) {
    float zr = zp[i];
    bf16x8 cv, sv;
#pragma unroll
    for (int t = 0; t < 8; t++) {
      float rev = fract_f(zr * (float)(hq * 8 + t + 1));
      cv[t] = (bf16_t)cos_rev(rev);
      sv[t] = (bf16_t)sin_rev(rev);
    }
    *(bf16x8*)(Ab + as0) = cv;
    *(bf16x8*)(Ab + as1) = sv;
  };

  // fixed A-fragment LDS offsets (wave-tile rows wm*32..+31)
  int offA[4];
#pragma unroll
  for (int ks = 0; ks < 2; ks++)
#pragma unroll
    for (int i4 = 0; i4 < 2; i4++)
      offA[ks * 2 + i4] = (wm * 32 + i4 * 16 + lr) * 64 + ((ks * 4 + g4) ^ (lr & 7)) * 8;

  f32x4 acc[2][4];
#pragma unroll
  for (int i = 0; i < 2; i++)
#pragma unroll
    for (int j = 0; j < 4; j++) acc[i][j] = f32x4{0.f, 0.f, 0.f, 0.f};

  auto domfma = [&](const bf16x8 (&af)[4], const bf16x8 (&b)[8]) {
    __builtin_amdgcn_s_setprio(1);
#pragma unroll
    for (int ks = 0; ks < 2; ks++)
#pragma unroll
      for (int i4 = 0; i4 < 2; i4++)
#pragma unroll
        for (int j = 0; j < 4; j++)
          acc[i4][j] = __builtin_amdgcn_mfma_f32_16x16x32_bf16(af[ks * 2 + i4], b[ks * 4 + j], acc[i4][j], 0, 0, 0);
    __builtin_amdgcn_s_setprio(0);
  };
  auto readA = [&](const bf16_t* Ac, bf16x8 (&af)[4]) {
#pragma unroll
    for (int t = 0; t < 4; t++) af[t] = *(const bf16x8*)(Ac + offA[t]);
  };

  bf16x8 bA_[8], bB_[8];
  __syncthreads();                      // zl visible
  loadB(0, bA_);
  genA(0, Asm[0]);
  asm volatile("s_waitcnt lgkmcnt(0)" ::: "memory");
  __builtin_amdgcn_s_barrier();

#pragma unroll 1
  for (int it = 0; it < 16; it++) {
    const int i = it * 2;
    bf16x8 af[4];
    if (i < 31) loadB(i + 1, bB_);
    readA(Asm[0], af);
    if (i < 31) genA(i + 1, Asm[1]);
    domfma(af, bA_);
    asm volatile("s_waitcnt lgkmcnt(0)" ::: "memory");
    __builtin_amdgcn_s_barrier();
    if (i + 2 < 32) loadB(i + 2, bA_);
    readA(Asm[1], af);
    if (i + 2 < 32) genA(i + 2, Asm[0]);
    domfma(af, bB_);
    asm volatile("s_waitcnt lgkmcnt(0)" ::: "memory");
    __builtin_amdgcn_s_barrier();
  }

  float* outp = fa.P[q];
#pragma unroll
  for (int i = 0; i < 2; i++)
#pragma unroll
    for (int j = 0; j < 4; j++) {
      int col = n0 + wn * 64 + j * 16 + lr;
#pragma unroll
      for (int r = 0; r < 4; r++) {
        int row = m0 + wm * 32 + i * 16 + g4 * 4 + r;
        outp[(size_t)row * 256 + col] = acc[i][j][r];
      }
    }
}

// ---------------- reduce 8 K-split partials + new_s epilogue (float4) -------
struct RArgs {
  const float* P[8];
  const float* fb; const float* tk; const float* s0;
  float* news; bf16_t* sob;
};

__global__ __launch_bounds__(256) void k_freduce(RArgs ra) {
  int stride = gridDim.x * blockDim.x;
  for (int qd = blockIdx.x * blockDim.x + threadIdx.x; qd < 262144; qd += stride) {
    int i = qd * 4, o = i & 255;
    float4 v = *(const float4*)(ra.P[0] + i);
#pragma unroll
    for (int c = 1; c < 8; c++) {
      float4 p = *(const float4*)(ra.P[c] + i);
      v.x += p.x; v.y += p.y; v.z += p.z; v.w += p.w;
    }
    v.x += ra.fb[o + 0]; v.y += ra.fb[o + 1]; v.z += ra.fb[o + 2]; v.w += ra.fb[o + 3];
    bf16x4 sb; sb[0] = (bf16_t)v.x; sb[1] = (bf16_t)v.y; sb[2] = (bf16_t)v.z; sb[3] = (bf16_t)v.w;
    *(bf16x4*)(ra.sob + i) = sb;
    float4 s = *(const float4*)(ra.s0 + i);
    float4 ns;
    ns.x = ra.tk[o + 0] * v.x + ra.tk[256 + o + 0] * s.x;
    ns.y = ra.tk[o + 1] * v.y + ra.tk[256 + o + 1] * s.y;
    ns.z = ra.tk[o + 2] * v.z + ra.tk[256 + o + 2] * s.z;
    ns.w = ra.tk[o + 3] * v.w + ra.tk[256 + o + 3] * s.w;
    *(float4*)(ra.news + i) = ns;
  }
}

// ---------------- h = LN(o * tanh(c)) ----------------
__global__ __launch_bounds__(256) void k_ln(const float* __restrict__ o,
                                            const float* __restrict__ tc,
                                            const float* __restrict__ lg,
                                            const float* __restrict__ lb,
                                            float* __restrict__ h) {
  int b = blockIdx.x, tid = threadIdx.x;
  float2 ov = *(const float2*)(o + (size_t)b * 512 + tid * 2);
  float2 tv = *(const float2*)(tc + (size_t)b * 512 + tid * 2);
  float h0 = ov.x * tv.x, h1 = ov.y * tv.y;
  float s = h0 + h1, ss = h0 * h0 + h1 * h1;
#pragma unroll
  for (int off = 32; off; off >>= 1) {
    s += __shfl_xor(s, off);
    ss += __shfl_xor(ss, off);
  }
  __shared__ float red[8];
  int wid = tid >> 6;
  if ((tid & 63) == 0) { red[wid] = s; red[4 + wid] = ss; }
  __syncthreads();
  s = red[0] + red[1] + red[2] + red[3];
  ss = red[4] + red[5] + red[6] + red[7];
  float mu = s * (1.f / 512.f);
  float var = ss * (1.f / 512.f) - mu * mu;
  float rs = rsqrtf(var + 1e-5f);
  int j = tid * 2;
  h[(size_t)b * 512 + j]     = (h0 - mu) * rs * lg[j]     + lb[j];
  h[(size_t)b * 512 + j + 1] = (h1 - mu) * rs * lg[j + 1] + lb[j + 1];
}

// ---------------- launcher ----------------
extern "C" void kernel_launch(void* const* d_in, const int* in_sizes, int n_in,
                              void* d_out, int out_size, void* d_ws, size_t ws_size,
                              hipStream_t stream) {
  const float* x    = (const float*)d_in[0];
  const float* h0   = (const float*)d_in[1];
  const float* c0   = (const float*)d_in[2];
  const float* s0   = (const float*)d_in[3];
  const float* Wk   = (const float*)d_in[4];
  const float* Wr   = (const float*)d_in[5];
  const float* bias = (const float*)d_in[6];
  const float* kx   = (const float*)d_in[7];
  const float* kh   = (const float*)d_in[8];
  const float* tk   = (const float*)d_in[9];
  const float* fc   = (const float*)d_in[10];
  const float* fb   = (const float*)d_in[11];
  const float* aw   = (const float*)d_in[12];
  const float* ab   = (const float*)d_in[13];
  const float* lg   = (const float*)d_in[14];
  const float* lbp  = (const float*)d_in[15];
  float* out = (float*)d_out;
  char* ws = (char*)d_ws;
  auto BF = [&](unsigned long long off) { return (bf16_t*)(ws + off); };
  auto FP = [&](unsigned long long off) { return (float*)(ws + off); };

  // fused conversions + fcb2 tiling + transposes
  k_prep<<<3456, 256, 0, stream>>>(x, h0, s0, fc, Wk, Wr, aw, kx, kh,
                                   BF(O_XHI), BF(O_XLO), BF(O_H0),
                                   BF(O_S0H), BF(O_S0L), BF(O_FCB),
                                   BF(O_KT), BF(O_RKT), BF(O_AWT),
                                   BF(O_KXH), BF(O_KXL), BF(O_KHH), BF(O_KHL));

  // fused gates GEMM + cell: c -> d_out[2M..4M), tanh(c) -> TC
  {
    GatesArgs ga{ BF(O_XHI), BF(O_H0), BF(O_KT), BF(O_RKT), bias, c0,
                  out + 2097152, FP(O_TC) };
    k_gates<<<dim3(4, 64), 512, 0, stream>>>(ga);
  }

  // agg GEMM (hi/lo split), output in revolutions
  {
    GArgs g{};
    g.p[0] = { BF(O_XHI), BF(O_KXH), 256, 256, 256 };
    g.p[1] = { BF(O_XHI), BF(O_KXL), 256, 256, 256 };
    g.p[2] = { BF(O_XLO), BF(O_KXH), 256, 256, 256 };
    g.p[3] = { BF(O_S0H), BF(O_KHH), 256, 256, 256 };
    g.p[4] = { BF(O_S0H), BF(O_KHL), 256, 256, 256 };
    g.p[5] = { BF(O_S0L), BF(O_KHH), 256, 256, 256 };
    g.np = 6; g.bias = nullptr; g.act = 0;
    g.out = FP(O_AGG); g.ldout = 256;
    k_gemm<64, 64><<<dim3(4, 64), 512, 0, stream>>>(g);
  }

  // Fourier KAN (q=8 K-split, 1024 blocks = 4/CU x 4 waves).
  FArgs fa;
  fa.agg = FP(O_AGG); fa.fcb2 = BF(O_FCB);
  fa.P[0] = FP(0ull);
  fa.P[1] = FP(4194304ull);
  fa.P[2] = FP(8388608ull);
  for (int c = 3; c < 8; c++) fa.P[c] = FP(O_P3 + (unsigned long long)(c - 3) * 4194304ull);
  k_fourier<<<1024, 256, 0, stream>>>(fa);

  // reduce partials, emit new_s (d_out[4M..5M)) + sub_out bf16
  RArgs ra;
  for (int c = 0; c < 8; c++) ra.P[c] = fa.P[c];
  ra.fb = fb; ra.tk = tk; ra.s0 = s0;
  ra.news = out + 4194304; ra.sob = BF(O_SOB);
  k_freduce<<<1024, 256, 0, stream>>>(ra);

  // out-proj GEMM: o = sigmoid(sub_out@agg_w + agg_b)   (O overlays FCB)
  {
    GArgs g{};
    g.p[0] = { BF(O_SOB), BF(O_AWT), 256, 256, 256 };
    g.np = 1; g.bias = ab; g.act = 1;
    g.out = FP(O_O); g.ldout = 512;
    k_gemm<64, 128><<<dim3(4, 64), 512, 0, stream>>>(g);
  }
  // h = LN(o * tanh(c)) -> d_out[0..2M)
  k_ln<<<4096, 256, 0, stream>>>(FP(O_O), FP(O_TC), lg, lbp, out);
}

// Round 14
// 113.737 us; speedup vs baseline: 1.0902x; 1.0609x over previous
//
#include <hip/hip_runtime.h>
#include <hip/hip_bf16.h>

typedef __bf16 bf16_t;
typedef __bf16 bf16x2 __attribute__((ext_vector_type(2)));
typedef __bf16 bf16x4 __attribute__((ext_vector_type(4)));
typedef __bf16 bf16x8 __attribute__((ext_vector_type(8)));
typedef float  f32x4  __attribute__((ext_vector_type(4)));

#define NB 4096
#define IN_DIM 256
#define HID 512
#define SUB 256
#define GRID_ 32

// ---------------- math helpers ----------------
__device__ __forceinline__ float fract_f(float x) {
#if __has_builtin(__builtin_amdgcn_fractf)
  return __builtin_amdgcn_fractf(x);
#else
  return x - floorf(x);
#endif
}
__device__ __forceinline__ float cos_rev(float rev) {
#if __has_builtin(__builtin_amdgcn_cosf)
  return __builtin_amdgcn_cosf(rev);
#else
  return __cosf(rev * 6.283185307179586f);
#endif
}
__device__ __forceinline__ float sin_rev(float rev) {
#if __has_builtin(__builtin_amdgcn_sinf)
  return __builtin_amdgcn_sinf(rev);
#else
  return __sinf(rev * 6.283185307179586f);
#endif
}
__device__ __forceinline__ float sigm(float v) { return 1.f / (1.f + __expf(-v)); }
__device__ __forceinline__ float fast_tanh(float x) {
  float e = __expf(2.f * x);
  return (e - 1.f) / (e + 1.f);
}
#define INV2PI 0.15915494309189535f

// ---------------- workspace layout (bytes), high-water 59.77MB ----------------
#define O_XHI   0ull
#define O_XLO   2097152ull
#define O_H0    4194304ull
#define O_S0H   8388608ull
#define O_S0L   10485760ull
#define O_FCB   12582912ull   // fcb2 tiled layout, 8.4MB
#define O_O     12582912ull   // bf16 o, overlays FCB (dead after k_fourier)
#define O_KT    20971520ull
#define O_RKT   21757952ull
#define O_AWT   23330816ull
#define O_KXH   23592960ull
#define O_KXL   23724032ull
#define O_KHH   23855104ull
#define O_KHL   23986176ull
#define O_TC    24117248ull   // bf16 tanh(c), 4MB
#define O_SOB   32505856ull
#define O_AGG   34603008ull
#define O_P3    38797312ull   // chunks 3..7, 5 x 4MB -> end 59768832

// ---------------- transpose-convert body ----------------
__device__ __forceinline__ void tconv_body(const float* __restrict__ src,
                                           bf16_t* __restrict__ hi,
                                           bf16_t* __restrict__ lo,
                                           int R, int C, int bx, int by,
                                           bool wantlo, float scale) {
  __shared__ float t[32][33];
  int c0 = bx * 32, r0 = by * 32;
  int tx = threadIdx.x & 31, ty = threadIdx.x >> 5;
#pragma unroll
  for (int rr = 0; rr < 4; rr++) {
    int r = ty + rr * 8;
    t[r][tx] = src[(size_t)(r0 + r) * C + c0 + tx];
  }
  __syncthreads();
#pragma unroll
  for (int rr = 0; rr < 4; rr++) {
    int cl = ty + rr * 8;
    float f = t[tx][cl] * scale;
    bf16_t h = (bf16_t)f;
    size_t oi = (size_t)(c0 + cl) * R + r0 + tx;
    hi[oi] = h;
    if (wantlo) lo[oi] = (bf16_t)(f - (float)h);
  }
}

// ---------------- fused prep (conversions + fcb2 tiling) + all transposes ----
__global__ __launch_bounds__(256) void k_prep(const float* __restrict__ x,
                                              const float* __restrict__ h0,
                                              const float* __restrict__ s0,
                                              const float* __restrict__ fc,
                                              const float* __restrict__ Wk,
                                              const float* __restrict__ Wr,
                                              const float* __restrict__ aw,
                                              const float* __restrict__ kx,
                                              const float* __restrict__ kh,
                                              bf16_t* __restrict__ xhi, bf16_t* __restrict__ xlo,
                                              bf16_t* __restrict__ h0b,
                                              bf16_t* __restrict__ s0h, bf16_t* __restrict__ s0l,
                                              bf16_t* __restrict__ fcb2,
                                              bf16_t* __restrict__ kt,
                                              bf16_t* __restrict__ rkt,
                                              bf16_t* __restrict__ awt,
                                              bf16_t* __restrict__ kxh, bf16_t* __restrict__ kxl,
                                              bf16_t* __restrict__ khh, bf16_t* __restrict__ khl) {
  int bid = blockIdx.x;
  if (bid < 2048) {
    for (int q = bid * 256 + threadIdx.x; q < 2097152; q += 524288) {
      if (q < 1048576) {
        const float* src; bf16_t* hi; bf16_t* lo = nullptr; int base;
        if (q < 262144)       { src = x;  hi = xhi; lo = xlo; base = q; }
        else if (q < 786432)  { src = h0; hi = h0b;           base = q - 262144; }
        else                  { src = s0; hi = s0h; lo = s0l; base = q - 786432; }
        float4 v = *(const float4*)(src + (size_t)base * 4);
        bf16x4 h; h[0] = (bf16_t)v.x; h[1] = (bf16_t)v.y; h[2] = (bf16_t)v.z; h[3] = (bf16_t)v.w;
        *(bf16x4*)(hi + (size_t)base * 4) = h;
        if (lo) {
          bf16x4 l;
          l[0] = (bf16_t)(v.x - (float)h[0]); l[1] = (bf16_t)(v.y - (float)h[1]);
          l[2] = (bf16_t)(v.z - (float)h[2]); l[3] = (bf16_t)(v.w - (float)h[3]);
          *(bf16x4*)(lo + (size_t)base * 4) = l;
        }
      } else {
        int f = q - 1048576;              // fc quad
        int e = f * 4;
        int g = e & 31, i = (e >> 5) & 255, o = (e >> 13) & 255, s = e >> 21;
        float4 v = *(const float4*)(fc + (size_t)e);
        bf16x4 h; h[0] = (bf16_t)v.x; h[1] = (bf16_t)v.y; h[2] = (bf16_t)v.z; h[3] = (bf16_t)v.w;
        int nb = o >> 7, wn = (o >> 6) & 1, j = (o >> 4) & 3, lr = o & 15;
        int g4 = g >> 3, t0 = g & 7;
        size_t idx = ((((((size_t)(i * 2 + nb) * 2 + wn) * 4 + j) * 2 + s) * 4 + g4) * 16 + lr) * 8 + t0;
        *(bf16x4*)(fcb2 + idx) = h;
      }
    }
  } else {
    int b = bid - 2048;
    if (b < 384)       { tconv_body(Wk, kt,  nullptr, 256, 1536, b % 48, b / 48, false, 1.f); }
    else if (b < 1152) { b -= 384;  tconv_body(Wr, rkt, nullptr, 512, 1536, b % 48, b / 48, false, 1.f); }
    else if (b < 1280) { b -= 1152; tconv_body(aw, awt, nullptr, 256, 512,  b % 16, b / 16, false, 1.f); }
    else if (b < 1344) { b -= 1280; tconv_body(kx, kxh, kxl,     256, 256,  b % 8,  b / 8,  true, INV2PI); }
    else               { b -= 1344; tconv_body(kh, khh, khl,     256, 256,  b % 8,  b / 8,  true, INV2PI); }
  }
}

// ---------------- generic multi-pass bf16 MFMA GEMM (stride 64 + XOR swz) ---
struct Pass { const bf16_t* A; const bf16_t* Bt; int K; int lda; int ldbt; };
struct GArgs {
  Pass p[6]; int np;
  const float* bias;
  int act;                  // 1 -> sigmoid(acc+bias)
  float* out; bf16_t* outb; int ldout;   // outb!=null -> write bf16
};

template<int BM, int BN>
__global__ __launch_bounds__(512) void k_gemm(GArgs g) {
  constexpr int MI = BM / 32;
  constexpr int NJ = BN / 64;
  constexpr int IA = (BM * 8) / 512;
  constexpr int IB = (BN * 8) / 512;
  __shared__ bf16_t smA[BM * 64];
  __shared__ bf16_t smB[BN * 64];
  const int tid = threadIdx.x;
  const int m0 = blockIdx.y * BM, n0 = blockIdx.x * BN;
  const int wv = tid >> 6, lane = tid & 63;
  const int wm = wv >> 2, wn = wv & 3;
  const int lr = lane & 15, g4 = lane >> 4;

  f32x4 acc[MI][NJ];
#pragma unroll
  for (int i = 0; i < MI; i++)
#pragma unroll
    for (int j = 0; j < NJ; j++) acc[i][j] = f32x4{0.f, 0.f, 0.f, 0.f};

  for (int ps = 0; ps < g.np; ps++) {
    const bf16_t* A = g.p[ps].A;
    const bf16_t* Bt = g.p[ps].Bt;
    const int K = g.p[ps].K, lda = g.p[ps].lda, ldbt = g.p[ps].ldbt;
    for (int k0 = 0; k0 < K; k0 += 64) {
      bf16x8 ar[IA], br[IB];
#pragma unroll
      for (int r = 0; r < IA; r++) {
        int task = tid + r * 512, row = task >> 3, t = task & 7, sf = t ^ (row & 7);
        ar[r] = *(const bf16x8*)(A + (size_t)(m0 + row) * lda + k0 + sf * 8);
      }
#pragma unroll
      for (int r = 0; r < IB; r++) {
        int task = tid + r * 512, row = task >> 3, t = task & 7, sf = t ^ (row & 7);
        br[r] = *(const bf16x8*)(Bt + (size_t)(n0 + row) * ldbt + k0 + sf * 8);
      }
      __syncthreads();
#pragma unroll
      for (int r = 0; r < IA; r++) {
        int task = tid + r * 512, row = task >> 3, t = task & 7;
        *(bf16x8*)(smA + row * 64 + t * 8) = ar[r];
      }
#pragma unroll
      for (int r = 0; r < IB; r++) {
        int task = tid + r * 512, row = task >> 3, t = task & 7;
        *(bf16x8*)(smB + row * 64 + t * 8) = br[r];
      }
      __syncthreads();
#pragma unroll
      for (int ks = 0; ks < 2; ks++) {
        bf16x8 af[MI], bfr[NJ];
#pragma unroll
        for (int i = 0; i < MI; i++) {
          int row = wm * (BM / 2) + i * 16 + lr;
          af[i] = *(const bf16x8*)(smA + row * 64 + ((ks * 4 + g4) ^ (lr & 7)) * 8);
        }
#pragma unroll
        for (int j = 0; j < NJ; j++) {
          int row = wn * (BN / 4) + j * 16 + lr;
          bfr[j] = *(const bf16x8*)(smB + row * 64 + ((ks * 4 + g4) ^ (lr & 7)) * 8);
        }
#pragma unroll
        for (int i = 0; i < MI; i++)
#pragma unroll
          for (int j = 0; j < NJ; j++)
            acc[i][j] = __builtin_amdgcn_mfma_f32_16x16x32_bf16(af[i], bfr[j], acc[i][j], 0, 0, 0);
      }
    }
  }
#pragma unroll
  for (int i = 0; i < MI; i++)
#pragma unroll
    for (int j = 0; j < NJ; j++) {
      int col = n0 + wn * (BN / 4) + j * 16 + lr;
      float bb = g.bias ? g.bias[col] : 0.f;
#pragma unroll
      for (int r = 0; r < 4; r++) {
        int row = m0 + wm * (BM / 2) + i * 16 + (lane >> 4) * 4 + r;
        float v = acc[i][j][r] + bb;
        if (g.act == 1) v = sigm(v);
        if (g.outb) g.outb[(size_t)row * g.ldout + col] = (bf16_t)v;
        else        g.out [(size_t)row * g.ldout + col] = v;
      }
    }
}

// ---------------- fused gates GEMM + cell state v2 (fine blocks) -------------
// BM=64, BN=64 cols x 3 gates, grid (8,64)=512 blocks, 256 thr 4 waves 2m x 2n.
// LDS 32KB -> 2+ independent blocks/CU. Cell epilogue: c fp32 (output),
// tanh(c) bf16.
struct GatesArgs {
  const bf16_t* xhi; const bf16_t* h0b; const bf16_t* kt; const bf16_t* rkt;
  const float* bias; const float* c0; float* c_out; bf16_t* tc;
};

__global__ __launch_bounds__(256, 2) void k_gates(GatesArgs ga) {
  __shared__ bf16_t smA[64 * 64];        // 8 KB
  __shared__ bf16_t smB[3 * 64 * 64];    // 24 KB
  const int tid = threadIdx.x;
  const int n0 = blockIdx.x * 64;        // 8 blocks cover 512 cols
  const int m0 = blockIdx.y * 64;
  const int wv = tid >> 6, lane = tid & 63;
  const int wm = wv >> 1, wn = wv & 1;
  const int lr = lane & 15, g4 = lane >> 4;

  f32x4 acc[3][2][2];
#pragma unroll
  for (int t = 0; t < 3; t++)
#pragma unroll
    for (int i = 0; i < 2; i++)
#pragma unroll
      for (int j = 0; j < 2; j++) acc[t][i][j] = f32x4{0.f, 0.f, 0.f, 0.f};

  for (int ps = 0; ps < 2; ps++) {
    const bf16_t* A  = ps ? ga.h0b : ga.xhi;
    const bf16_t* Bt = ps ? ga.rkt : ga.kt;
    const int K = ps ? 512 : 256, ld = K;
    for (int k0 = 0; k0 < K; k0 += 64) {
      bf16x8 ar[2], br[6];
#pragma unroll
      for (int r = 0; r < 2; r++) {
        int task = tid + r * 256, row = task >> 3, t = task & 7, sf = t ^ (row & 7);
        ar[r] = *(const bf16x8*)(A + (size_t)(m0 + row) * ld + k0 + sf * 8);
      }
#pragma unroll
      for (int r = 0; r < 6; r++) {
        int task = tid + r * 256;
        int gate = task >> 9, rem = task & 511, o = rem >> 3, t = rem & 7, sf = t ^ (o & 7);
        br[r] = *(const bf16x8*)(Bt + (size_t)(gate * 512 + n0 + o) * ld + k0 + sf * 8);
      }
      __syncthreads();
#pragma unroll
      for (int r = 0; r < 2; r++) {
        int task = tid + r * 256, row = task >> 3, t = task & 7;
        *(bf16x8*)(smA + row * 64 + t * 8) = ar[r];
      }
#pragma unroll
      for (int r = 0; r < 6; r++) {
        int task = tid + r * 256;
        int gate = task >> 9, rem = task & 511, o = rem >> 3, t = rem & 7;
        *(bf16x8*)(smB + (gate * 64 + o) * 64 + t * 8) = br[r];
      }
      __syncthreads();
#pragma unroll
      for (int ks = 0; ks < 2; ks++) {
        bf16x8 af[2];
#pragma unroll
        for (int i = 0; i < 2; i++) {
          int row = wm * 32 + i * 16 + lr;
          af[i] = *(const bf16x8*)(smA + row * 64 + ((ks * 4 + g4) ^ (lr & 7)) * 8);
        }
#pragma unroll
        for (int t = 0; t < 3; t++) {
          bf16x8 bfr[2];
#pragma unroll
          for (int j = 0; j < 2; j++) {
            int row = wn * 32 + j * 16 + lr;
            bfr[j] = *(const bf16x8*)(smB + (t * 64 + row) * 64 + ((ks * 4 + g4) ^ (lr & 7)) * 8);
          }
#pragma unroll
          for (int i = 0; i < 2; i++)
#pragma unroll
            for (int j = 0; j < 2; j++)
              acc[t][i][j] = __builtin_amdgcn_mfma_f32_16x16x32_bf16(af[i], bfr[j], acc[t][i][j], 0, 0, 0);
        }
      }
    }
  }
#pragma unroll
  for (int i = 0; i < 2; i++)
#pragma unroll
    for (int j = 0; j < 2; j++) {
      int col = n0 + wn * 32 + j * 16 + lr;
      float bi = ga.bias[col], bf_ = ga.bias[512 + col], bc = ga.bias[1024 + col];
#pragma unroll
      for (int r = 0; r < 4; r++) {
        int row = m0 + wm * 32 + i * 16 + g4 * 4 + r;
        size_t idx = (size_t)row * 512 + col;
        float iv = sigm(acc[0][i][j][r] + bi);
        float fv = sigm(acc[1][i][j][r] + bf_);
        float cc = sigm(acc[2][i][j][r] + bc);
        float cv = fv * ga.c0[idx] + iv * fast_tanh(cc);
        ga.c_out[idx] = cv;
        ga.tc[idx] = (bf16_t)fast_tanh(cv);
      }
    }
}

// ---------------- Fourier-KAN GEMM v9 (measured 45.5us) ----------------
// BM=64, BN=128, q=8 K-split, grid 1024 = 4 blocks/CU. 128 thr = 2 waves
// (wave-tile 64x64, acc[4][4]). B: coalesced reg loads from fcb2 (named
// dbuf banks); A: shared trig-gen into swizzled LDS dbuf. One lgkm-only
// barrier/iter. LDS 24.8KB.
struct FArgs { const float* agg; const bf16_t* fcb2; float* P[8]; };

__global__ __launch_bounds__(128, 2) void k_fourier(FArgs fa) {
  __shared__ float  zl[64 * 33];        // 8.4 KB
  __shared__ bf16_t Asm[2][64 * 64];    // 16 KB
  const int tid = threadIdx.x;
  const int bx = blockIdx.x;            // 1024 blocks; q = bx&7 = XCD id
  const int q = bx & 7, nb = (bx >> 3) & 1, mb = bx >> 4;
  const int m0 = mb * 64, n0 = nb * 128, i0 = q * 32;
  const int wv = tid >> 6, lane = tid & 63;
  const int wn = wv;
  const int lr = lane & 15, g4 = lane >> 4;

  // stage z tile [64 rows x 32 i] -> zl (stride 33)
#pragma unroll
  for (int r = 0; r < 4; r++) {
    int task = tid + r * 128, row = task >> 3, seg = task & 7;
    float4 v = *(const float4*)(fa.agg + (size_t)(m0 + row) * 256 + i0 + seg * 4);
    zl[row * 33 + seg * 4 + 0] = v.x;
    zl[row * 33 + seg * 4 + 1] = v.y;
    zl[row * 33 + seg * 4 + 2] = v.z;
    zl[row * 33 + seg * 4 + 3] = v.w;
  }

  // B: coalesced 16B/lane loads from fcb2 (strides: i 16384, nb 8192,
  // wn 4096, j 1024, ks 512, lane*8).
  const bf16_t* pB = fa.fcb2 + (size_t)i0 * 16384 + nb * 8192 + wn * 4096 + lane * 8;
  auto loadB = [&](int i, bf16x8 (&b)[8]) {
#pragma unroll
    for (int ks = 0; ks < 2; ks++)
#pragma unroll
      for (int j = 0; j < 4; j++)
        b[ks * 4 + j] = *(const bf16x8*)(pB + (size_t)i * 16384 + j * 1024 + ks * 512);
  };

  // A trig-gen (shared): row=tid>>1 (0..63), hp=tid&1 -> g4 in {2hp,2hp+1}.
  const int grow = tid >> 1, hp = tid & 1;
  const float* zp = zl + grow * 33;
  const int as0 = grow * 64 + (((2 * hp    ) ^ (grow & 7)) * 8);
  const int as1 = grow * 64 + (((2 * hp + 1) ^ (grow & 7)) * 8);
  const int as2 = grow * 64 + (((4 + 2 * hp) ^ (grow & 7)) * 8);
  const int as3 = grow * 64 + (((5 + 2 * hp) ^ (grow & 7)) * 8);
  auto genA = [&](int i, bf16_t* Ab) {
    float zr = zp[i];
    bf16x8 c0v, c1v, s0v, s1v;
#pragma unroll
    for (int t = 0; t < 8; t++) {
      float r0 = fract_f(zr * (float)(hp * 16 + t + 1));
      float r1 = fract_f(zr * (float)(hp * 16 + 8 + t + 1));
      c0v[t] = (bf16_t)cos_rev(r0); s0v[t] = (bf16_t)sin_rev(r0);
      c1v[t] = (bf16_t)cos_rev(r1); s1v[t] = (bf16_t)sin_rev(r1);
    }
    *(bf16x8*)(Ab + as0) = c0v;
    *(bf16x8*)(Ab + as1) = c1v;
    *(bf16x8*)(Ab + as2) = s0v;
    *(bf16x8*)(Ab + as3) = s1v;
  };

  // fixed A-fragment LDS offsets (rows 0..63)
  int offA[8];
#pragma unroll
  for (int ks = 0; ks < 2; ks++)
#pragma unroll
    for (int i4 = 0; i4 < 4; i4++)
      offA[ks * 4 + i4] = (i4 * 16 + lr) * 64 + ((ks * 4 + g4) ^ (lr & 7)) * 8;

  f32x4 acc[4][4];
#pragma unroll
  for (int i = 0; i < 4; i++)
#pragma unroll
    for (int j = 0; j < 4; j++) acc[i][j] = f32x4{0.f, 0.f, 0.f, 0.f};

  auto domfma = [&](const bf16x8 (&af)[8], const bf16x8 (&b)[8]) {
    __builtin_amdgcn_s_setprio(1);
#pragma unroll
    for (int ks = 0; ks < 2; ks++)
#pragma unroll
      for (int i4 = 0; i4 < 4; i4++)
#pragma unroll
        for (int j = 0; j < 4; j++)
          acc[i4][j] = __builtin_amdgcn_mfma_f32_16x16x32_bf16(af[ks * 4 + i4], b[ks * 4 + j], acc[i4][j], 0, 0, 0);
    __builtin_amdgcn_s_setprio(0);
  };
  auto readA = [&](const bf16_t* Ac, bf16x8 (&af)[8]) {
#pragma unroll
    for (int t = 0; t < 8; t++) af[t] = *(const bf16x8*)(Ac + offA[t]);
  };

  bf16x8 bA_[8], bB_[8];
  __syncthreads();                      // zl visible
  loadB(0, bA_);
  genA(0, Asm[0]);
  asm volatile("s_waitcnt lgkmcnt(0)" ::: "memory");
  __builtin_amdgcn_s_barrier();

#pragma unroll 1
  for (int it = 0; it < 16; it++) {
    const int i = it * 2;
    bf16x8 af[8];
    if (i < 31) loadB(i + 1, bB_);
    readA(Asm[0], af);
    if (i < 31) genA(i + 1, Asm[1]);
    domfma(af, bA_);
    asm volatile("s_waitcnt lgkmcnt(0)" ::: "memory");
    __builtin_amdgcn_s_barrier();
    if (i + 2 < 32) loadB(i + 2, bA_);
    readA(Asm[1], af);
    if (i + 2 < 32) genA(i + 2, Asm[0]);
    domfma(af, bB_);
    asm volatile("s_waitcnt lgkmcnt(0)" ::: "memory");
    __builtin_amdgcn_s_barrier();
  }

  float* outp = fa.P[q];
#pragma unroll
  for (int i = 0; i < 4; i++)
#pragma unroll
    for (int j = 0; j < 4; j++) {
      int col = n0 + wn * 64 + j * 16 + lr;
#pragma unroll
      for (int r = 0; r < 4; r++) {
        int row = m0 + i * 16 + g4 * 4 + r;
        outp[(size_t)row * 256 + col] = acc[i][j][r];
      }
    }
}

// ---------------- reduce 8 K-split partials + new_s epilogue (float4) -------
struct RArgs {
  const float* P[8];
  const float* fb; const float* tk; const float* s0;
  float* news; bf16_t* sob;
};

__global__ __launch_bounds__(256) void k_freduce(RArgs ra) {
  int stride = gridDim.x * blockDim.x;
  for (int qd = blockIdx.x * blockDim.x + threadIdx.x; qd < 262144; qd += stride) {
    int i = qd * 4, o = i & 255;
    float4 v = *(const float4*)(ra.P[0] + i);
#pragma unroll
    for (int c = 1; c < 8; c++) {
      float4 p = *(const float4*)(ra.P[c] + i);
      v.x += p.x; v.y += p.y; v.z += p.z; v.w += p.w;
    }
    v.x += ra.fb[o + 0]; v.y += ra.fb[o + 1]; v.z += ra.fb[o + 2]; v.w += ra.fb[o + 3];
    bf16x4 sb; sb[0] = (bf16_t)v.x; sb[1] = (bf16_t)v.y; sb[2] = (bf16_t)v.z; sb[3] = (bf16_t)v.w;
    *(bf16x4*)(ra.sob + i) = sb;
    float4 s = *(const float4*)(ra.s0 + i);
    float4 ns;
    ns.x = ra.tk[o + 0] * v.x + ra.tk[256 + o + 0] * s.x;
    ns.y = ra.tk[o + 1] * v.y + ra.tk[256 + o + 1] * s.y;
    ns.z = ra.tk[o + 2] * v.z + ra.tk[256 + o + 2] * s.z;
    ns.w = ra.tk[o + 3] * v.w + ra.tk[256 + o + 3] * s.w;
    *(float4*)(ra.news + i) = ns;
  }
}

// ---------------- h = LN(o * tanh(c)), o/tc bf16 ----------------
__global__ __launch_bounds__(256) void k_ln(const bf16_t* __restrict__ o,
                                            const bf16_t* __restrict__ tc,
                                            const float* __restrict__ lg,
                                            const float* __restrict__ lb,
                                            float* __restrict__ h) {
  int b = blockIdx.x, tid = threadIdx.x;
  bf16x2 ov = *(const bf16x2*)(o + (size_t)b * 512 + tid * 2);
  bf16x2 tv = *(const bf16x2*)(tc + (size_t)b * 512 + tid * 2);
  float h0 = (float)ov[0] * (float)tv[0], h1 = (float)ov[1] * (float)tv[1];
  float s = h0 + h1, ss = h0 * h0 + h1 * h1;
#pragma unroll
  for (int off = 32; off; off >>= 1) {
    s += __shfl_xor(s, off);
    ss += __shfl_xor(ss, off);
  }
  __shared__ float red[8];
  int wid = tid >> 6;
  if ((tid & 63) == 0) { red[wid] = s; red[4 + wid] = ss; }
  __syncthreads();
  s = red[0] + red[1] + red[2] + red[3];
  ss = red[4] + red[5] + red[6] + red[7];
  float mu = s * (1.f / 512.f);
  float var = ss * (1.f / 512.f) - mu * mu;
  float rs = rsqrtf(var + 1e-5f);
  int j = tid * 2;
  h[(size_t)b * 512 + j]     = (h0 - mu) * rs * lg[j]     + lb[j];
  h[(size_t)b * 512 + j + 1] = (h1 - mu) * rs * lg[j + 1] + lb[j + 1];
}

// ---------------- launcher ----------------
extern "C" void kernel_launch(void* const* d_in, const int* in_sizes, int n_in,
                              void* d_out, int out_size, void* d_ws, size_t ws_size,
                              hipStream_t stream) {
  const float* x    = (const float*)d_in[0];
  const float* h0   = (const float*)d_in[1];
  const float* c0   = (const float*)d_in[2];
  const float* s0   = (const float*)d_in[3];
  const float* Wk   = (const float*)d_in[4];
  const float* Wr   = (const float*)d_in[5];
  const float* bias = (const float*)d_in[6];
  const float* kx   = (const float*)d_in[7];
  const float* kh   = (const float*)d_in[8];
  const float* tk   = (const float*)d_in[9];
  const float* fc   = (const float*)d_in[10];
  const float* fb   = (const float*)d_in[11];
  const float* aw   = (const float*)d_in[12];
  const float* ab   = (const float*)d_in[13];
  const float* lg   = (const float*)d_in[14];
  const float* lbp  = (const float*)d_in[15];
  float* out = (float*)d_out;
  char* ws = (char*)d_ws;
  auto BF = [&](unsigned long long off) { return (bf16_t*)(ws + off); };
  auto FP = [&](unsigned long long off) { return (float*)(ws + off); };

  // fused conversions + fcb2 tiling + transposes
  k_prep<<<3456, 256, 0, stream>>>(x, h0, s0, fc, Wk, Wr, aw, kx, kh,
                                   BF(O_XHI), BF(O_XLO), BF(O_H0),
                                   BF(O_S0H), BF(O_S0L), BF(O_FCB),
                                   BF(O_KT), BF(O_RKT), BF(O_AWT),
                                   BF(O_KXH), BF(O_KXL), BF(O_KHH), BF(O_KHL));

  // fused gates GEMM + cell: c -> d_out[2M..4M) fp32, tanh(c) -> TC bf16
  {
    GatesArgs ga{ BF(O_XHI), BF(O_H0), BF(O_KT), BF(O_RKT), bias, c0,
                  out + 2097152, BF(O_TC) };
    k_gates<<<dim3(8, 64), 256, 0, stream>>>(ga);
  }

  // agg GEMM (hi/lo split), output in revolutions
  {
    GArgs g{};
    g.p[0] = { BF(O_XHI), BF(O_KXH), 256, 256, 256 };
    g.p[1] = { BF(O_XHI), BF(O_KXL), 256, 256, 256 };
    g.p[2] = { BF(O_XLO), BF(O_KXH), 256, 256, 256 };
    g.p[3] = { BF(O_S0H), BF(O_KHH), 256, 256, 256 };
    g.p[4] = { BF(O_S0H), BF(O_KHL), 256, 256, 256 };
    g.p[5] = { BF(O_S0L), BF(O_KHH), 256, 256, 256 };
    g.np = 6; g.bias = nullptr; g.act = 0;
    g.out = FP(O_AGG); g.outb = nullptr; g.ldout = 256;
    k_gemm<64, 64><<<dim3(4, 64), 512, 0, stream>>>(g);
  }

  // Fourier KAN (q=8 K-split, 1024 blocks = 4/CU).
  FArgs fa;
  fa.agg = FP(O_AGG); fa.fcb2 = BF(O_FCB);
  fa.P[0] = FP(0ull);
  fa.P[1] = FP(4194304ull);
  fa.P[2] = FP(8388608ull);
  for (int c = 3; c < 8; c++) fa.P[c] = FP(O_P3 + (unsigned long long)(c - 3) * 4194304ull);
  k_fourier<<<1024, 128, 0, stream>>>(fa);

  // reduce partials, emit new_s (d_out[4M..5M)) + sub_out bf16
  RArgs ra;
  for (int c = 0; c < 8; c++) ra.P[c] = fa.P[c];
  ra.fb = fb; ra.tk = tk; ra.s0 = s0;
  ra.news = out + 4194304; ra.sob = BF(O_SOB);
  k_freduce<<<1024, 256, 0, stream>>>(ra);

  // out-proj GEMM: o = sigmoid(sub_out@agg_w + agg_b), bf16 (O overlays FCB)
  {
    GArgs g{};
    g.p[0] = { BF(O_SOB), BF(O_AWT), 256, 256, 256 };
    g.np = 1; g.bias = ab; g.act = 1;
    g.out = nullptr; g.outb = BF(O_O); g.ldout = 512;
    k_gemm<64, 128><<<dim3(4, 64), 512, 0, stream>>>(g);
  }
  // h = LN(o * tanh(c)) -> d_out[0..2M)
  k_ln<<<4096, 256, 0, stream>>>(BF(O_O), BF(O_TC), lg, lbp, out);
}

// Round 15
// 96.405 us; speedup vs baseline: 1.2862x; 1.1798x over previous
//
#include <hip/hip_runtime.h>
#include <hip/hip_bf16.h>

typedef __bf16 bf16_t;
typedef __bf16 bf16x2 __attribute__((ext_vector_type(2)));
typedef __bf16 bf16x4 __attribute__((ext_vector_type(4)));
typedef __bf16 bf16x8 __attribute__((ext_vector_type(8)));
typedef float  f32x4  __attribute__((ext_vector_type(4)));

#define NB 4096
#define IN_DIM 256
#define HID 512
#define SUB 256
#define GRID_ 32

// ---------------- math helpers ----------------
__device__ __forceinline__ float fract_f(float x) {
#if __has_builtin(__builtin_amdgcn_fractf)
  return __builtin_amdgcn_fractf(x);
#else
  return x - floorf(x);
#endif
}
__device__ __forceinline__ float cos_rev(float rev) {
#if __has_builtin(__builtin_amdgcn_cosf)
  return __builtin_amdgcn_cosf(rev);
#else
  return __cosf(rev * 6.283185307179586f);
#endif
}
__device__ __forceinline__ float sin_rev(float rev) {
#if __has_builtin(__builtin_amdgcn_sinf)
  return __builtin_amdgcn_sinf(rev);
#else
  return __sinf(rev * 6.283185307179586f);
#endif
}
__device__ __forceinline__ float sigm(float v) { return 1.f / (1.f + __expf(-v)); }
__device__ __forceinline__ float fast_tanh(float x) {
  float e = __expf(2.f * x);
  return (e - 1.f) / (e + 1.f);
}
#define INV2PI 0.15915494309189535f

// ---------------- workspace layout (bytes), high-water 59.77MB ----------------
// P (bf16, 2MB/chunk): chunks 0-5 overlay XHI/XLO/H0/S0H/S0L (dead after
// k_gatesagg); chunks 6,7 in O_P3. O (bf16 o) overlays FCB after k_fourier.
#define O_XHI   0ull
#define O_XLO   2097152ull
#define O_H0    4194304ull
#define O_S0H   8388608ull
#define O_S0L   10485760ull
#define O_FCB   12582912ull   // fcb2 tiled layout, 8.4MB
#define O_O     12582912ull
#define O_KT    20971520ull
#define O_RKT   21757952ull
#define O_AWT   23330816ull
#define O_KXH   23592960ull
#define O_KXL   23724032ull
#define O_KHH   23855104ull
#define O_KHL   23986176ull
#define O_TC    24117248ull   // bf16 tanh(c), 4MB
#define O_SOB   32505856ull
#define O_AGG   34603008ull
#define O_P3    38797312ull

// ---------------- transpose-convert body ----------------
__device__ __forceinline__ void tconv_body(const float* __restrict__ src,
                                           bf16_t* __restrict__ hi,
                                           bf16_t* __restrict__ lo,
                                           int R, int C, int bx, int by,
                                           bool wantlo, float scale) {
  __shared__ float t[32][33];
  int c0 = bx * 32, r0 = by * 32;
  int tx = threadIdx.x & 31, ty = threadIdx.x >> 5;
#pragma unroll
  for (int rr = 0; rr < 4; rr++) {
    int r = ty + rr * 8;
    t[r][tx] = src[(size_t)(r0 + r) * C + c0 + tx];
  }
  __syncthreads();
#pragma unroll
  for (int rr = 0; rr < 4; rr++) {
    int cl = ty + rr * 8;
    float f = t[tx][cl] * scale;
    bf16_t h = (bf16_t)f;
    size_t oi = (size_t)(c0 + cl) * R + r0 + tx;
    hi[oi] = h;
    if (wantlo) lo[oi] = (bf16_t)(f - (float)h);
  }
}

// ---------------- fused prep (conversions + fcb2 tiling) + all transposes ----
__global__ __launch_bounds__(256) void k_prep(const float* __restrict__ x,
                                              const float* __restrict__ h0,
                                              const float* __restrict__ s0,
                                              const float* __restrict__ fc,
                                              const float* __restrict__ Wk,
                                              const float* __restrict__ Wr,
                                              const float* __restrict__ aw,
                                              const float* __restrict__ kx,
                                              const float* __restrict__ kh,
                                              bf16_t* __restrict__ xhi, bf16_t* __restrict__ xlo,
                                              bf16_t* __restrict__ h0b,
                                              bf16_t* __restrict__ s0h, bf16_t* __restrict__ s0l,
                                              bf16_t* __restrict__ fcb2,
                                              bf16_t* __restrict__ kt,
                                              bf16_t* __restrict__ rkt,
                                              bf16_t* __restrict__ awt,
                                              bf16_t* __restrict__ kxh, bf16_t* __restrict__ kxl,
                                              bf16_t* __restrict__ khh, bf16_t* __restrict__ khl) {
  int bid = blockIdx.x;
  if (bid < 2048) {
    for (int q = bid * 256 + threadIdx.x; q < 2097152; q += 524288) {
      if (q < 1048576) {
        const float* src; bf16_t* hi; bf16_t* lo = nullptr; int base;
        if (q < 262144)       { src = x;  hi = xhi; lo = xlo; base = q; }
        else if (q < 786432)  { src = h0; hi = h0b;           base = q - 262144; }
        else                  { src = s0; hi = s0h; lo = s0l; base = q - 786432; }
        float4 v = *(const float4*)(src + (size_t)base * 4);
        bf16x4 h; h[0] = (bf16_t)v.x; h[1] = (bf16_t)v.y; h[2] = (bf16_t)v.z; h[3] = (bf16_t)v.w;
        *(bf16x4*)(hi + (size_t)base * 4) = h;
        if (lo) {
          bf16x4 l;
          l[0] = (bf16_t)(v.x - (float)h[0]); l[1] = (bf16_t)(v.y - (float)h[1]);
          l[2] = (bf16_t)(v.z - (float)h[2]); l[3] = (bf16_t)(v.w - (float)h[3]);
          *(bf16x4*)(lo + (size_t)base * 4) = l;
        }
      } else {
        int f = q - 1048576;              // fc quad
        int e = f * 4;
        int g = e & 31, i = (e >> 5) & 255, o = (e >> 13) & 255, s = e >> 21;
        float4 v = *(const float4*)(fc + (size_t)e);
        bf16x4 h; h[0] = (bf16_t)v.x; h[1] = (bf16_t)v.y; h[2] = (bf16_t)v.z; h[3] = (bf16_t)v.w;
        int nb = o >> 7, wn = (o >> 6) & 1, j = (o >> 4) & 3, lr = o & 15;
        int g4 = g >> 3, t0 = g & 7;
        size_t idx = ((((((size_t)(i * 2 + nb) * 2 + wn) * 4 + j) * 2 + s) * 4 + g4) * 16 + lr) * 8 + t0;
        *(bf16x4*)(fcb2 + idx) = h;
      }
    }
  } else {
    int b = bid - 2048;
    if (b < 384)       { tconv_body(Wk, kt,  nullptr, 256, 1536, b % 48, b / 48, false, 1.f); }
    else if (b < 1152) { b -= 384;  tconv_body(Wr, rkt, nullptr, 512, 1536, b % 48, b / 48, false, 1.f); }
    else if (b < 1280) { b -= 1152; tconv_body(aw, awt, nullptr, 256, 512,  b % 16, b / 16, false, 1.f); }
    else if (b < 1344) { b -= 1280; tconv_body(kx, kxh, kxl,     256, 256,  b % 8,  b / 8,  true, INV2PI); }
    else               { b -= 1344; tconv_body(kh, khh, khl,     256, 256,  b % 8,  b / 8,  true, INV2PI); }
  }
}

// ---------------- generic multi-pass bf16 MFMA GEMM (stride 64 + XOR swz) ---
struct Pass { const bf16_t* A; const bf16_t* Bt; int K; int lda; int ldbt; };
struct GArgs {
  Pass p[6]; int np;
  const float* bias;
  int act;                  // 1 -> sigmoid(acc+bias)
  float* out; bf16_t* outb; int ldout;   // outb!=null -> write bf16
};

template<int BM, int BN>
__global__ __launch_bounds__(512) void k_gemm(GArgs g) {
  constexpr int MI = BM / 32;
  constexpr int NJ = BN / 64;
  constexpr int IA = (BM * 8) / 512;
  constexpr int IB = (BN * 8) / 512;
  __shared__ bf16_t smA[BM * 64];
  __shared__ bf16_t smB[BN * 64];
  const int tid = threadIdx.x;
  const int m0 = blockIdx.y * BM, n0 = blockIdx.x * BN;
  const int wv = tid >> 6, lane = tid & 63;
  const int wm = wv >> 2, wn = wv & 3;
  const int lr = lane & 15, g4 = lane >> 4;

  f32x4 acc[MI][NJ];
#pragma unroll
  for (int i = 0; i < MI; i++)
#pragma unroll
    for (int j = 0; j < NJ; j++) acc[i][j] = f32x4{0.f, 0.f, 0.f, 0.f};

  for (int ps = 0; ps < g.np; ps++) {
    const bf16_t* A = g.p[ps].A;
    const bf16_t* Bt = g.p[ps].Bt;
    const int K = g.p[ps].K, lda = g.p[ps].lda, ldbt = g.p[ps].ldbt;
    for (int k0 = 0; k0 < K; k0 += 64) {
      bf16x8 ar[IA], br[IB];
#pragma unroll
      for (int r = 0; r < IA; r++) {
        int task = tid + r * 512, row = task >> 3, t = task & 7, sf = t ^ (row & 7);
        ar[r] = *(const bf16x8*)(A + (size_t)(m0 + row) * lda + k0 + sf * 8);
      }
#pragma unroll
      for (int r = 0; r < IB; r++) {
        int task = tid + r * 512, row = task >> 3, t = task & 7, sf = t ^ (row & 7);
        br[r] = *(const bf16x8*)(Bt + (size_t)(n0 + row) * ldbt + k0 + sf * 8);
      }
      __syncthreads();
#pragma unroll
      for (int r = 0; r < IA; r++) {
        int task = tid + r * 512, row = task >> 3, t = task & 7;
        *(bf16x8*)(smA + row * 64 + t * 8) = ar[r];
      }
#pragma unroll
      for (int r = 0; r < IB; r++) {
        int task = tid + r * 512, row = task >> 3, t = task & 7;
        *(bf16x8*)(smB + row * 64 + t * 8) = br[r];
      }
      __syncthreads();
#pragma unroll
      for (int ks = 0; ks < 2; ks++) {
        bf16x8 af[MI], bfr[NJ];
#pragma unroll
        for (int i = 0; i < MI; i++) {
          int row = wm * (BM / 2) + i * 16 + lr;
          af[i] = *(const bf16x8*)(smA + row * 64 + ((ks * 4 + g4) ^ (lr & 7)) * 8);
        }
#pragma unroll
        for (int j = 0; j < NJ; j++) {
          int row = wn * (BN / 4) + j * 16 + lr;
          bfr[j] = *(const bf16x8*)(smB + row * 64 + ((ks * 4 + g4) ^ (lr & 7)) * 8);
        }
#pragma unroll
        for (int i = 0; i < MI; i++)
#pragma unroll
          for (int j = 0; j < NJ; j++)
            acc[i][j] = __builtin_amdgcn_mfma_f32_16x16x32_bf16(af[i], bfr[j], acc[i][j], 0, 0, 0);
      }
    }
  }
#pragma unroll
  for (int i = 0; i < MI; i++)
#pragma unroll
    for (int j = 0; j < NJ; j++) {
      int col = n0 + wn * (BN / 4) + j * 16 + lr;
      float bb = g.bias ? g.bias[col] : 0.f;
#pragma unroll
      for (int r = 0; r < 4; r++) {
        int row = m0 + wm * (BM / 2) + i * 16 + (lane >> 4) * 4 + r;
        float v = acc[i][j][r] + bb;
        if (g.act == 1) v = sigm(v);
        if (g.outb) g.outb[(size_t)row * g.ldout + col] = (bf16_t)v;
        else        g.out [(size_t)row * g.ldout + col] = v;
      }
    }
}

// ---------------- merged gates GEMM+cell  AND  agg GEMM ----------------
// 768 blocks, 256 thr, 4 waves 2m x 2n, 64x64 tiles.
// blocks 0..511: gates (n0=(b&7)*64, m0=(b>>3)*64), cell epilogue.
// blocks 512..767: agg 6-pass hi/lo GEMM (n0=(b&3)*64, m0=(b>>2)*64).
struct GAArgs {
  const bf16_t* xhi; const bf16_t* h0b; const bf16_t* kt; const bf16_t* rkt;
  const float* bias; const float* c0; float* c_out; bf16_t* tc;
  const bf16_t* aggA[6]; const bf16_t* aggB[6];
  float* agg;
};

__global__ __launch_bounds__(256, 2) void k_gatesagg(GAArgs ga) {
  __shared__ bf16_t smA[64 * 64];        // 8 KB
  __shared__ bf16_t smB[3 * 64 * 64];    // 24 KB
  const int tid = threadIdx.x;
  const int wv = tid >> 6, lane = tid & 63;
  const int wm = wv >> 1, wn = wv & 1;
  const int lr = lane & 15, g4 = lane >> 4;

  if (blockIdx.x < 512) {
    // ---- gates + cell ----
    const int b = blockIdx.x;
    const int n0 = (b & 7) * 64, m0 = (b >> 3) * 64;
    f32x4 acc[3][2][2];
#pragma unroll
    for (int t = 0; t < 3; t++)
#pragma unroll
      for (int i = 0; i < 2; i++)
#pragma unroll
        for (int j = 0; j < 2; j++) acc[t][i][j] = f32x4{0.f, 0.f, 0.f, 0.f};

    for (int ps = 0; ps < 2; ps++) {
      const bf16_t* A  = ps ? ga.h0b : ga.xhi;
      const bf16_t* Bt = ps ? ga.rkt : ga.kt;
      const int K = ps ? 512 : 256, ld = K;
      for (int k0 = 0; k0 < K; k0 += 64) {
        bf16x8 ar[2], br[6];
#pragma unroll
        for (int r = 0; r < 2; r++) {
          int task = tid + r * 256, row = task >> 3, t = task & 7, sf = t ^ (row & 7);
          ar[r] = *(const bf16x8*)(A + (size_t)(m0 + row) * ld + k0 + sf * 8);
        }
#pragma unroll
        for (int r = 0; r < 6; r++) {
          int task = tid + r * 256;
          int gate = task >> 9, rem = task & 511, o = rem >> 3, t = rem & 7, sf = t ^ (o & 7);
          br[r] = *(const bf16x8*)(Bt + (size_t)(gate * 512 + n0 + o) * ld + k0 + sf * 8);
        }
        __syncthreads();
#pragma unroll
        for (int r = 0; r < 2; r++) {
          int task = tid + r * 256, row = task >> 3, t = task & 7;
          *(bf16x8*)(smA + row * 64 + t * 8) = ar[r];
        }
#pragma unroll
        for (int r = 0; r < 6; r++) {
          int task = tid + r * 256;
          int gate = task >> 9, rem = task & 511, o = rem >> 3, t = rem & 7;
          *(bf16x8*)(smB + (gate * 64 + o) * 64 + t * 8) = br[r];
        }
        __syncthreads();
#pragma unroll
        for (int ks = 0; ks < 2; ks++) {
          bf16x8 af[2];
#pragma unroll
          for (int i = 0; i < 2; i++) {
            int row = wm * 32 + i * 16 + lr;
            af[i] = *(const bf16x8*)(smA + row * 64 + ((ks * 4 + g4) ^ (lr & 7)) * 8);
          }
#pragma unroll
          for (int t = 0; t < 3; t++) {
            bf16x8 bfr[2];
#pragma unroll
            for (int j = 0; j < 2; j++) {
              int row = wn * 32 + j * 16 + lr;
              bfr[j] = *(const bf16x8*)(smB + (t * 64 + row) * 64 + ((ks * 4 + g4) ^ (lr & 7)) * 8);
            }
#pragma unroll
            for (int i = 0; i < 2; i++)
#pragma unroll
              for (int j = 0; j < 2; j++)
                acc[t][i][j] = __builtin_amdgcn_mfma_f32_16x16x32_bf16(af[i], bfr[j], acc[t][i][j], 0, 0, 0);
          }
        }
      }
    }
#pragma unroll
    for (int i = 0; i < 2; i++)
#pragma unroll
      for (int j = 0; j < 2; j++) {
        int col = n0 + wn * 32 + j * 16 + lr;
        float bi = ga.bias[col], bf_ = ga.bias[512 + col], bc = ga.bias[1024 + col];
#pragma unroll
        for (int r = 0; r < 4; r++) {
          int row = m0 + wm * 32 + i * 16 + g4 * 4 + r;
          size_t idx = (size_t)row * 512 + col;
          float iv = sigm(acc[0][i][j][r] + bi);
          float fv = sigm(acc[1][i][j][r] + bf_);
          float cc = sigm(acc[2][i][j][r] + bc);
          float cv = fv * ga.c0[idx] + iv * fast_tanh(cc);
          ga.c_out[idx] = cv;
          ga.tc[idx] = (bf16_t)fast_tanh(cv);
        }
      }
  } else {
    // ---- agg: 6-pass hi/lo GEMM, 64x64 tile ----
    const int b = blockIdx.x - 512;
    const int n0 = (b & 3) * 64, m0 = (b >> 2) * 64;
    f32x4 acc[2][2];
#pragma unroll
    for (int i = 0; i < 2; i++)
#pragma unroll
      for (int j = 0; j < 2; j++) acc[i][j] = f32x4{0.f, 0.f, 0.f, 0.f};

    for (int ps = 0; ps < 6; ps++) {
      const bf16_t* A  = ga.aggA[ps];
      const bf16_t* Bt = ga.aggB[ps];
      for (int k0 = 0; k0 < 256; k0 += 64) {
        bf16x8 ar[2], br[2];
#pragma unroll
        for (int r = 0; r < 2; r++) {
          int task = tid + r * 256, row = task >> 3, t = task & 7, sf = t ^ (row & 7);
          ar[r] = *(const bf16x8*)(A  + (size_t)(m0 + row) * 256 + k0 + sf * 8);
          br[r] = *(const bf16x8*)(Bt + (size_t)(n0 + row) * 256 + k0 + sf * 8);
        }
        __syncthreads();
#pragma unroll
        for (int r = 0; r < 2; r++) {
          int task = tid + r * 256, row = task >> 3, t = task & 7;
          *(bf16x8*)(smA + row * 64 + t * 8) = ar[r];
          *(bf16x8*)(smB + row * 64 + t * 8) = br[r];
        }
        __syncthreads();
#pragma unroll
        for (int ks = 0; ks < 2; ks++) {
          bf16x8 af[2], bfr[2];
#pragma unroll
          for (int i = 0; i < 2; i++) {
            int row = wm * 32 + i * 16 + lr;
            af[i] = *(const bf16x8*)(smA + row * 64 + ((ks * 4 + g4) ^ (lr & 7)) * 8);
          }
#pragma unroll
          for (int j = 0; j < 2; j++) {
            int row = wn * 32 + j * 16 + lr;
            bfr[j] = *(const bf16x8*)(smB + row * 64 + ((ks * 4 + g4) ^ (lr & 7)) * 8);
          }
#pragma unroll
          for (int i = 0; i < 2; i++)
#pragma unroll
            for (int j = 0; j < 2; j++)
              acc[i][j] = __builtin_amdgcn_mfma_f32_16x16x32_bf16(af[i], bfr[j], acc[i][j], 0, 0, 0);
        }
      }
    }
#pragma unroll
    for (int i = 0; i < 2; i++)
#pragma unroll
      for (int j = 0; j < 2; j++) {
        int col = n0 + wn * 32 + j * 16 + lr;
#pragma unroll
        for (int r = 0; r < 4; r++) {
          int row = m0 + wm * 32 + i * 16 + g4 * 4 + r;
          ga.agg[(size_t)row * 256 + col] = acc[i][j][r];
        }
      }
  }
}

// ---------------- Fourier-KAN GEMM v9 (bf16 P output) ----------------
// BM=64, BN=128, q=8 K-split, grid 1024 = 4 blocks/CU. 128 thr = 2 waves
// (wave-tile 64x64, acc[4][4]). B: coalesced reg loads from fcb2; A: shared
// trig-gen into swizzled LDS dbuf. One lgkm-only barrier/iter. LDS 24.8KB.
struct FArgs { const float* agg; const bf16_t* fcb2; bf16_t* P[8]; };

__global__ __launch_bounds__(128, 2) void k_fourier(FArgs fa) {
  __shared__ float  zl[64 * 33];        // 8.4 KB
  __shared__ bf16_t Asm[2][64 * 64];    // 16 KB
  const int tid = threadIdx.x;
  const int bx = blockIdx.x;            // 1024 blocks; q = bx&7 = XCD id
  const int q = bx & 7, nb = (bx >> 3) & 1, mb = bx >> 4;
  const int m0 = mb * 64, n0 = nb * 128, i0 = q * 32;
  const int wv = tid >> 6, lane = tid & 63;
  const int wn = wv;
  const int lr = lane & 15, g4 = lane >> 4;

  // stage z tile [64 rows x 32 i] -> zl (stride 33)
#pragma unroll
  for (int r = 0; r < 4; r++) {
    int task = tid + r * 128, row = task >> 3, seg = task & 7;
    float4 v = *(const float4*)(fa.agg + (size_t)(m0 + row) * 256 + i0 + seg * 4);
    zl[row * 33 + seg * 4 + 0] = v.x;
    zl[row * 33 + seg * 4 + 1] = v.y;
    zl[row * 33 + seg * 4 + 2] = v.z;
    zl[row * 33 + seg * 4 + 3] = v.w;
  }

  // B: coalesced 16B/lane loads from fcb2 (strides: i 16384, nb 8192,
  // wn 4096, j 1024, ks 512, lane*8).
  const bf16_t* pB = fa.fcb2 + (size_t)i0 * 16384 + nb * 8192 + wn * 4096 + lane * 8;
  auto loadB = [&](int i, bf16x8 (&b)[8]) {
#pragma unroll
    for (int ks = 0; ks < 2; ks++)
#pragma unroll
      for (int j = 0; j < 4; j++)
        b[ks * 4 + j] = *(const bf16x8*)(pB + (size_t)i * 16384 + j * 1024 + ks * 512);
  };

  // A trig-gen (shared): row=tid>>1 (0..63), hp=tid&1 -> g4 in {2hp,2hp+1}.
  const int grow = tid >> 1, hp = tid & 1;
  const float* zp = zl + grow * 33;
  const int as0 = grow * 64 + (((2 * hp    ) ^ (grow & 7)) * 8);
  const int as1 = grow * 64 + (((2 * hp + 1) ^ (grow & 7)) * 8);
  const int as2 = grow * 64 + (((4 + 2 * hp) ^ (grow & 7)) * 8);
  const int as3 = grow * 64 + (((5 + 2 * hp) ^ (grow & 7)) * 8);
  auto genA = [&](int i, bf16_t* Ab) {
    float zr = zp[i];
    bf16x8 c0v, c1v, s0v, s1v;
#pragma unroll
    for (int t = 0; t < 8; t++) {
      float r0 = fract_f(zr * (float)(hp * 16 + t + 1));
      float r1 = fract_f(zr * (float)(hp * 16 + 8 + t + 1));
      c0v[t] = (bf16_t)cos_rev(r0); s0v[t] = (bf16_t)sin_rev(r0);
      c1v[t] = (bf16_t)cos_rev(r1); s1v[t] = (bf16_t)sin_rev(r1);
    }
    *(bf16x8*)(Ab + as0) = c0v;
    *(bf16x8*)(Ab + as1) = c1v;
    *(bf16x8*)(Ab + as2) = s0v;
    *(bf16x8*)(Ab + as3) = s1v;
  };

  // fixed A-fragment LDS offsets (rows 0..63)
  int offA[8];
#pragma unroll
  for (int ks = 0; ks < 2; ks++)
#pragma unroll
    for (int i4 = 0; i4 < 4; i4++)
      offA[ks * 4 + i4] = (i4 * 16 + lr) * 64 + ((ks * 4 + g4) ^ (lr & 7)) * 8;

  f32x4 acc[4][4];
#pragma unroll
  for (int i = 0; i < 4; i++)
#pragma unroll
    for (int j = 0; j < 4; j++) acc[i][j] = f32x4{0.f, 0.f, 0.f, 0.f};

  auto domfma = [&](const bf16x8 (&af)[8], const bf16x8 (&b)[8]) {
    __builtin_amdgcn_s_setprio(1);
#pragma unroll
    for (int ks = 0; ks < 2; ks++)
#pragma unroll
      for (int i4 = 0; i4 < 4; i4++)
#pragma unroll
        for (int j = 0; j < 4; j++)
          acc[i4][j] = __builtin_amdgcn_mfma_f32_16x16x32_bf16(af[ks * 4 + i4], b[ks * 4 + j], acc[i4][j], 0, 0, 0);
    __builtin_amdgcn_s_setprio(0);
  };
  auto readA = [&](const bf16_t* Ac, bf16x8 (&af)[8]) {
#pragma unroll
    for (int t = 0; t < 8; t++) af[t] = *(const bf16x8*)(Ac + offA[t]);
  };

  bf16x8 bA_[8], bB_[8];
  __syncthreads();                      // zl visible
  loadB(0, bA_);
  genA(0, Asm[0]);
  asm volatile("s_waitcnt lgkmcnt(0)" ::: "memory");
  __builtin_amdgcn_s_barrier();

#pragma unroll 1
  for (int it = 0; it < 16; it++) {
    const int i = it * 2;
    bf16x8 af[8];
    if (i < 31) loadB(i + 1, bB_);
    readA(Asm[0], af);
    if (i < 31) genA(i + 1, Asm[1]);
    domfma(af, bA_);
    asm volatile("s_waitcnt lgkmcnt(0)" ::: "memory");
    __builtin_amdgcn_s_barrier();
    if (i + 2 < 32) loadB(i + 2, bA_);
    readA(Asm[1], af);
    if (i + 2 < 32) genA(i + 2, Asm[0]);
    domfma(af, bB_);
    asm volatile("s_waitcnt lgkmcnt(0)" ::: "memory");
    __builtin_amdgcn_s_barrier();
  }

  bf16_t* outp = fa.P[q];
#pragma unroll
  for (int i = 0; i < 4; i++)
#pragma unroll
    for (int j = 0; j < 4; j++) {
      int col = n0 + wn * 64 + j * 16 + lr;
#pragma unroll
      for (int r = 0; r < 4; r++) {
        int row = m0 + i * 16 + g4 * 4 + r;
        outp[(size_t)row * 256 + col] = (bf16_t)acc[i][j][r];
      }
    }
}

// ---------------- reduce 8 bf16 K-split partials + new_s epilogue -----------
struct RArgs {
  const bf16_t* P[8];
  const float* fb; const float* tk; const float* s0;
  float* news; bf16_t* sob;
};

__global__ __launch_bounds__(256) void k_freduce(RArgs ra) {
  int stride = gridDim.x * blockDim.x;
  for (int qd = blockIdx.x * blockDim.x + threadIdx.x; qd < 262144; qd += stride) {
    int i = qd * 4, o = i & 255;
    float4 v = {0.f, 0.f, 0.f, 0.f};
#pragma unroll
    for (int c = 0; c < 8; c++) {
      bf16x4 p = *(const bf16x4*)(ra.P[c] + i);
      v.x += (float)p[0]; v.y += (float)p[1]; v.z += (float)p[2]; v.w += (float)p[3];
    }
    v.x += ra.fb[o + 0]; v.y += ra.fb[o + 1]; v.z += ra.fb[o + 2]; v.w += ra.fb[o + 3];
    bf16x4 sb; sb[0] = (bf16_t)v.x; sb[1] = (bf16_t)v.y; sb[2] = (bf16_t)v.z; sb[3] = (bf16_t)v.w;
    *(bf16x4*)(ra.sob + i) = sb;
    float4 s = *(const float4*)(ra.s0 + i);
    float4 ns;
    ns.x = ra.tk[o + 0] * v.x + ra.tk[256 + o + 0] * s.x;
    ns.y = ra.tk[o + 1] * v.y + ra.tk[256 + o + 1] * s.y;
    ns.z = ra.tk[o + 2] * v.z + ra.tk[256 + o + 2] * s.z;
    ns.w = ra.tk[o + 3] * v.w + ra.tk[256 + o + 3] * s.w;
    *(float4*)(ra.news + i) = ns;
  }
}

// ---------------- h = LN(o * tanh(c)), o/tc bf16 ----------------
__global__ __launch_bounds__(256) void k_ln(const bf16_t* __restrict__ o,
                                            const bf16_t* __restrict__ tc,
                                            const float* __restrict__ lg,
                                            const float* __restrict__ lb,
                                            float* __restrict__ h) {
  int b = blockIdx.x, tid = threadIdx.x;
  bf16x2 ov = *(const bf16x2*)(o + (size_t)b * 512 + tid * 2);
  bf16x2 tv = *(const bf16x2*)(tc + (size_t)b * 512 + tid * 2);
  float h0 = (float)ov[0] * (float)tv[0], h1 = (float)ov[1] * (float)tv[1];
  float s = h0 + h1, ss = h0 * h0 + h1 * h1;
#pragma unroll
  for (int off = 32; off; off >>= 1) {
    s += __shfl_xor(s, off);
    ss += __shfl_xor(ss, off);
  }
  __shared__ float red[8];
  int wid = tid >> 6;
  if ((tid & 63) == 0) { red[wid] = s; red[4 + wid] = ss; }
  __syncthreads();
  s = red[0] + red[1] + red[2] + red[3];
  ss = red[4] + red[5] + red[6] + red[7];
  float mu = s * (1.f / 512.f);
  float var = ss * (1.f / 512.f) - mu * mu;
  float rs = rsqrtf(var + 1e-5f);
  int j = tid * 2;
  h[(size_t)b * 512 + j]     = (h0 - mu) * rs * lg[j]     + lb[j];
  h[(size_t)b * 512 + j + 1] = (h1 - mu) * rs * lg[j + 1] + lb[j + 1];
}

// ---------------- launcher ----------------
extern "C" void kernel_launch(void* const* d_in, const int* in_sizes, int n_in,
                              void* d_out, int out_size, void* d_ws, size_t ws_size,
                              hipStream_t stream) {
  const float* x    = (const float*)d_in[0];
  const float* h0   = (const float*)d_in[1];
  const float* c0   = (const float*)d_in[2];
  const float* s0   = (const float*)d_in[3];
  const float* Wk   = (const float*)d_in[4];
  const float* Wr   = (const float*)d_in[5];
  const float* bias = (const float*)d_in[6];
  const float* kx   = (const float*)d_in[7];
  const float* kh   = (const float*)d_in[8];
  const float* tk   = (const float*)d_in[9];
  const float* fc   = (const float*)d_in[10];
  const float* fb   = (const float*)d_in[11];
  const float* aw   = (const float*)d_in[12];
  const float* ab   = (const float*)d_in[13];
  const float* lg   = (const float*)d_in[14];
  const float* lbp  = (const float*)d_in[15];
  float* out = (float*)d_out;
  char* ws = (char*)d_ws;
  auto BF = [&](unsigned long long off) { return (bf16_t*)(ws + off); };
  auto FP = [&](unsigned long long off) { return (float*)(ws + off); };

  // fused conversions + fcb2 tiling + transposes
  k_prep<<<3456, 256, 0, stream>>>(x, h0, s0, fc, Wk, Wr, aw, kx, kh,
                                   BF(O_XHI), BF(O_XLO), BF(O_H0),
                                   BF(O_S0H), BF(O_S0L), BF(O_FCB),
                                   BF(O_KT), BF(O_RKT), BF(O_AWT),
                                   BF(O_KXH), BF(O_KXL), BF(O_KHH), BF(O_KHL));

  // merged gates+cell and agg GEMMs (768 blocks)
  {
    GAArgs ga{};
    ga.xhi = BF(O_XHI); ga.h0b = BF(O_H0); ga.kt = BF(O_KT); ga.rkt = BF(O_RKT);
    ga.bias = bias; ga.c0 = c0; ga.c_out = out + 2097152; ga.tc = BF(O_TC);
    ga.aggA[0] = BF(O_XHI); ga.aggB[0] = BF(O_KXH);
    ga.aggA[1] = BF(O_XHI); ga.aggB[1] = BF(O_KXL);
    ga.aggA[2] = BF(O_XLO); ga.aggB[2] = BF(O_KXH);
    ga.aggA[3] = BF(O_S0H); ga.aggB[3] = BF(O_KHH);
    ga.aggA[4] = BF(O_S0H); ga.aggB[4] = BF(O_KHL);
    ga.aggA[5] = BF(O_S0L); ga.aggB[5] = BF(O_KHH);
    ga.agg = FP(O_AGG);
    k_gatesagg<<<768, 256, 0, stream>>>(ga);
  }

  // Fourier KAN (q=8 K-split, 1024 blocks = 4/CU). P bf16, chunks 0-5
  // overlay XHI/XLO/H0/S0H/S0L (dead after k_gatesagg), 6-7 in O_P3.
  FArgs fa;
  fa.agg = FP(O_AGG); fa.fcb2 = BF(O_FCB);
  for (int c = 0; c < 6; c++) fa.P[c] = BF((unsigned long long)c * 2097152ull);
  fa.P[6] = BF(O_P3);
  fa.P[7] = BF(O_P3 + 2097152ull);
  k_fourier<<<1024, 128, 0, stream>>>(fa);

  // reduce partials, emit new_s (d_out[4M..5M)) + sub_out bf16
  RArgs ra;
  for (int c = 0; c < 8; c++) ra.P[c] = fa.P[c];
  ra.fb = fb; ra.tk = tk; ra.s0 = s0;
  ra.news = out + 4194304; ra.sob = BF(O_SOB);
  k_freduce<<<1024, 256, 0, stream>>>(ra);

  // out-proj GEMM: o = sigmoid(sub_out@agg_w + agg_b), bf16 (O overlays FCB)
  {
    GArgs g{};
    g.p[0] = { BF(O_SOB), BF(O_AWT), 256, 256, 256 };
    g.np = 1; g.bias = ab; g.act = 1;
    g.out = nullptr; g.outb = BF(O_O); g.ldout = 512;
    k_gemm<64, 128><<<dim3(4, 64), 512, 0, stream>>>(g);
  }
  // h = LN(o * tanh(c)) -> d_out[0..2M)
  k_ln<<<4096, 256, 0, stream>>>(BF(O_O), BF(O_TC), lg, lbp, out);
}

// Round 16
// 95.577 us; speedup vs baseline: 1.2973x; 1.0087x over previous
//
#include <hip/hip_runtime.h>
#include <hip/hip_bf16.h>

typedef __bf16 bf16_t;
typedef __bf16 bf16x2 __attribute__((ext_vector_type(2)));
typedef __bf16 bf16x4 __attribute__((ext_vector_type(4)));
typedef __bf16 bf16x8 __attribute__((ext_vector_type(8)));
typedef float  f32x4  __attribute__((ext_vector_type(4)));

#define NB 4096
#define IN_DIM 256
#define HID 512
#define SUB 256
#define GRID_ 32

// ---------------- math helpers ----------------
__device__ __forceinline__ float fract_f(float x) {
#if __has_builtin(__builtin_amdgcn_fractf)
  return __builtin_amdgcn_fractf(x);
#else
  return x - floorf(x);
#endif
}
__device__ __forceinline__ float cos_rev(float rev) {
#if __has_builtin(__builtin_amdgcn_cosf)
  return __builtin_amdgcn_cosf(rev);
#else
  return __cosf(rev * 6.283185307179586f);
#endif
}
__device__ __forceinline__ float sin_rev(float rev) {
#if __has_builtin(__builtin_amdgcn_sinf)
  return __builtin_amdgcn_sinf(rev);
#else
  return __sinf(rev * 6.283185307179586f);
#endif
}
__device__ __forceinline__ float sigm(float v) { return 1.f / (1.f + __expf(-v)); }
__device__ __forceinline__ float fast_tanh(float x) {
  float e = __expf(2.f * x);
  return (e - 1.f) / (e + 1.f);
}
#define INV2PI 0.15915494309189535f

// ---------------- workspace layout (bytes), high-water 59.77MB ----------------
// P (bf16, 2MB/chunk): chunks 0-5 overlay XHI/XLO/H0/S0H/S0L (dead after
// k_gatesagg); chunks 6,7 in O_P3. O (bf16 o) overlays FCB after k_fourier.
#define O_XHI   0ull
#define O_XLO   2097152ull
#define O_H0    4194304ull
#define O_S0H   8388608ull
#define O_S0L   10485760ull
#define O_FCB   12582912ull   // fcb2 tiled layout, 8.4MB
#define O_O     12582912ull
#define O_KT    20971520ull
#define O_RKT   21757952ull
#define O_AWT   23330816ull
#define O_KXH   23592960ull
#define O_KXL   23724032ull
#define O_KHH   23855104ull
#define O_KHL   23986176ull
#define O_TC    24117248ull   // bf16 tanh(c), 4MB
#define O_SOB   32505856ull
#define O_AGG   34603008ull
#define O_P3    38797312ull

// ---------------- transpose-convert body ----------------
__device__ __forceinline__ void tconv_body(const float* __restrict__ src,
                                           bf16_t* __restrict__ hi,
                                           bf16_t* __restrict__ lo,
                                           int R, int C, int bx, int by,
                                           bool wantlo, float scale) {
  __shared__ float t[32][33];
  int c0 = bx * 32, r0 = by * 32;
  int tx = threadIdx.x & 31, ty = threadIdx.x >> 5;
#pragma unroll
  for (int rr = 0; rr < 4; rr++) {
    int r = ty + rr * 8;
    t[r][tx] = src[(size_t)(r0 + r) * C + c0 + tx];
  }
  __syncthreads();
#pragma unroll
  for (int rr = 0; rr < 4; rr++) {
    int cl = ty + rr * 8;
    float f = t[tx][cl] * scale;
    bf16_t h = (bf16_t)f;
    size_t oi = (size_t)(c0 + cl) * R + r0 + tx;
    hi[oi] = h;
    if (wantlo) lo[oi] = (bf16_t)(f - (float)h);
  }
}

// ---------------- fused prep: conversions + LDS-tiled fcb2 + transposes -----
// blocks 0..1023:      x/h0/s0 conversions (float4, grid-stride).
// blocks 1024..3071:   fc -> fcb2, one (s, o-tile64, i) tile per block via
//                      LDS (reads 128B segments, writes 1KB coalesced).
// blocks 3072..4479:   the 5 weight transposes.
__global__ __launch_bounds__(256) void k_prep(const float* __restrict__ x,
                                              const float* __restrict__ h0,
                                              const float* __restrict__ s0,
                                              const float* __restrict__ fc,
                                              const float* __restrict__ Wk,
                                              const float* __restrict__ Wr,
                                              const float* __restrict__ aw,
                                              const float* __restrict__ kx,
                                              const float* __restrict__ kh,
                                              bf16_t* __restrict__ xhi, bf16_t* __restrict__ xlo,
                                              bf16_t* __restrict__ h0b,
                                              bf16_t* __restrict__ s0h, bf16_t* __restrict__ s0l,
                                              bf16_t* __restrict__ fcb2,
                                              bf16_t* __restrict__ kt,
                                              bf16_t* __restrict__ rkt,
                                              bf16_t* __restrict__ awt,
                                              bf16_t* __restrict__ kxh, bf16_t* __restrict__ kxl,
                                              bf16_t* __restrict__ khh, bf16_t* __restrict__ khl) {
  int bid = blockIdx.x;
  if (bid < 1024) {
    for (int q = bid * 256 + threadIdx.x; q < 1048576; q += 262144) {
      const float* src; bf16_t* hi; bf16_t* lo = nullptr; int base;
      if (q < 262144)       { src = x;  hi = xhi; lo = xlo; base = q; }
      else if (q < 786432)  { src = h0; hi = h0b;           base = q - 262144; }
      else                  { src = s0; hi = s0h; lo = s0l; base = q - 786432; }
      float4 v = *(const float4*)(src + (size_t)base * 4);
      bf16x4 h; h[0] = (bf16_t)v.x; h[1] = (bf16_t)v.y; h[2] = (bf16_t)v.z; h[3] = (bf16_t)v.w;
      *(bf16x4*)(hi + (size_t)base * 4) = h;
      if (lo) {
        bf16x4 l;
        l[0] = (bf16_t)(v.x - (float)h[0]); l[1] = (bf16_t)(v.y - (float)h[1]);
        l[2] = (bf16_t)(v.z - (float)h[2]); l[3] = (bf16_t)(v.w - (float)h[3]);
        *(bf16x4*)(lo + (size_t)base * 4) = l;
      }
    }
  } else if (bid < 3072) {
    // fcb2 tile: tt -> (s, o-tile, i). fc[s][o][i][g], o0 = ot*64.
    __shared__ float tf[64 * 36];       // 9.2 KB, stride 36 (aligned, 2-way)
    int tt = bid - 1024;
    int s = tt & 1, ot = (tt >> 1) & 3, i = tt >> 3;
    int o0 = ot * 64, nbb = ot >> 1, wnn = ot & 1;
    int row = threadIdx.x >> 2, col = (threadIdx.x & 3) * 8;
    const float* src = fc + ((size_t)s << 21) + ((size_t)(o0 + row) << 13) +
                       ((size_t)i << 5) + col;
    float4 v0 = *(const float4*)(src);
    float4 v1 = *(const float4*)(src + 4);
    *(float4*)(tf + row * 36 + col) = v0;
    *(float4*)(tf + row * 36 + col + 4) = v1;
    __syncthreads();
    // output octet per thread: lr = tid&15, g4 = (tid>>4)&3, j = tid>>6
    int lr = threadIdx.x & 15, g4 = (threadIdx.x >> 4) & 3, j = threadIdx.x >> 6;
    const float* rp = tf + (j * 16 + lr) * 36 + g4 * 8;
    float4 a = *(const float4*)(rp);
    float4 b = *(const float4*)(rp + 4);
    bf16x8 h;
    h[0] = (bf16_t)a.x; h[1] = (bf16_t)a.y; h[2] = (bf16_t)a.z; h[3] = (bf16_t)a.w;
    h[4] = (bf16_t)b.x; h[5] = (bf16_t)b.y; h[6] = (bf16_t)b.z; h[7] = (bf16_t)b.w;
    size_t idx = (size_t)i * 16384 + nbb * 8192 + wnn * 4096 + j * 1024 +
                 s * 512 + g4 * 128 + lr * 8;
    *(bf16x8*)(fcb2 + idx) = h;
  } else {
    int b = bid - 3072;
    if (b < 384)       { tconv_body(Wk, kt,  nullptr, 256, 1536, b % 48, b / 48, false, 1.f); }
    else if (b < 1152) { b -= 384;  tconv_body(Wr, rkt, nullptr, 512, 1536, b % 48, b / 48, false, 1.f); }
    else if (b < 1280) { b -= 1152; tconv_body(aw, awt, nullptr, 256, 512,  b % 16, b / 16, false, 1.f); }
    else if (b < 1344) { b -= 1280; tconv_body(kx, kxh, kxl,     256, 256,  b % 8,  b / 8,  true, INV2PI); }
    else               { b -= 1344; tconv_body(kh, khh, khl,     256, 256,  b % 8,  b / 8,  true, INV2PI); }
  }
}

// ---------------- generic multi-pass bf16 MFMA GEMM (stride 64 + XOR swz) ---
struct Pass { const bf16_t* A; const bf16_t* Bt; int K; int lda; int ldbt; };
struct GArgs {
  Pass p[6]; int np;
  const float* bias;
  int act;                  // 1 -> sigmoid(acc+bias)
  float* out; bf16_t* outb; int ldout;   // outb!=null -> write bf16
};

template<int BM, int BN>
__global__ __launch_bounds__(512) void k_gemm(GArgs g) {
  constexpr int MI = BM / 32;
  constexpr int NJ = BN / 64;
  constexpr int IA = (BM * 8) / 512;
  constexpr int IB = (BN * 8) / 512;
  __shared__ bf16_t smA[BM * 64];
  __shared__ bf16_t smB[BN * 64];
  const int tid = threadIdx.x;
  const int m0 = blockIdx.y * BM, n0 = blockIdx.x * BN;
  const int wv = tid >> 6, lane = tid & 63;
  const int wm = wv >> 2, wn = wv & 3;
  const int lr = lane & 15, g4 = lane >> 4;

  f32x4 acc[MI][NJ];
#pragma unroll
  for (int i = 0; i < MI; i++)
#pragma unroll
    for (int j = 0; j < NJ; j++) acc[i][j] = f32x4{0.f, 0.f, 0.f, 0.f};

  for (int ps = 0; ps < g.np; ps++) {
    const bf16_t* A = g.p[ps].A;
    const bf16_t* Bt = g.p[ps].Bt;
    const int K = g.p[ps].K, lda = g.p[ps].lda, ldbt = g.p[ps].ldbt;
    for (int k0 = 0; k0 < K; k0 += 64) {
      bf16x8 ar[IA], br[IB];
#pragma unroll
      for (int r = 0; r < IA; r++) {
        int task = tid + r * 512, row = task >> 3, t = task & 7, sf = t ^ (row & 7);
        ar[r] = *(const bf16x8*)(A + (size_t)(m0 + row) * lda + k0 + sf * 8);
      }
#pragma unroll
      for (int r = 0; r < IB; r++) {
        int task = tid + r * 512, row = task >> 3, t = task & 7, sf = t ^ (row & 7);
        br[r] = *(const bf16x8*)(Bt + (size_t)(n0 + row) * ldbt + k0 + sf * 8);
      }
      __syncthreads();
#pragma unroll
      for (int r = 0; r < IA; r++) {
        int task = tid + r * 512, row = task >> 3, t = task & 7;
        *(bf16x8*)(smA + row * 64 + t * 8) = ar[r];
      }
#pragma unroll
      for (int r = 0; r < IB; r++) {
        int task = tid + r * 512, row = task >> 3, t = task & 7;
        *(bf16x8*)(smB + row * 64 + t * 8) = br[r];
      }
      __syncthreads();
#pragma unroll
      for (int ks = 0; ks < 2; ks++) {
        bf16x8 af[MI], bfr[NJ];
#pragma unroll
        for (int i = 0; i < MI; i++) {
          int row = wm * (BM / 2) + i * 16 + lr;
          af[i] = *(const bf16x8*)(smA + row * 64 + ((ks * 4 + g4) ^ (lr & 7)) * 8);
        }
#pragma unroll
        for (int j = 0; j < NJ; j++) {
          int row = wn * (BN / 4) + j * 16 + lr;
          bfr[j] = *(const bf16x8*)(smB + row * 64 + ((ks * 4 + g4) ^ (lr & 7)) * 8);
        }
#pragma unroll
        for (int i = 0; i < MI; i++)
#pragma unroll
          for (int j = 0; j < NJ; j++)
            acc[i][j] = __builtin_amdgcn_mfma_f32_16x16x32_bf16(af[i], bfr[j], acc[i][j], 0, 0, 0);
      }
    }
  }
#pragma unroll
  for (int i = 0; i < MI; i++)
#pragma unroll
    for (int j = 0; j < NJ; j++) {
      int col = n0 + wn * (BN / 4) + j * 16 + lr;
      float bb = g.bias ? g.bias[col] : 0.f;
#pragma unroll
      for (int r = 0; r < 4; r++) {
        int row = m0 + wm * (BM / 2) + i * 16 + (lane >> 4) * 4 + r;
        float v = acc[i][j][r] + bb;
        if (g.act == 1) v = sigm(v);
        if (g.outb) g.outb[(size_t)row * g.ldout + col] = (bf16_t)v;
        else        g.out [(size_t)row * g.ldout + col] = v;
      }
    }
}

// ---------------- merged gates GEMM+cell  AND  agg GEMM ----------------
// 768 blocks, 256 thr, 4 waves 2m x 2n, 64x64 tiles.
// blocks 0..511: gates (n0=(b&7)*64, m0=(b>>3)*64), cell epilogue.
// blocks 512..767: agg 6-pass hi/lo GEMM (n0=(b&3)*64, m0=(b>>2)*64).
struct GAArgs {
  const bf16_t* xhi; const bf16_t* h0b; const bf16_t* kt; const bf16_t* rkt;
  const float* bias; const float* c0; float* c_out; bf16_t* tc;
  const bf16_t* aggA[6]; const bf16_t* aggB[6];
  float* agg;
};

__global__ __launch_bounds__(256, 2) void k_gatesagg(GAArgs ga) {
  __shared__ bf16_t smA[64 * 64];        // 8 KB
  __shared__ bf16_t smB[3 * 64 * 64];    // 24 KB
  const int tid = threadIdx.x;
  const int wv = tid >> 6, lane = tid & 63;
  const int wm = wv >> 1, wn = wv & 1;
  const int lr = lane & 15, g4 = lane >> 4;

  if (blockIdx.x < 512) {
    // ---- gates + cell ----
    const int b = blockIdx.x;
    const int n0 = (b & 7) * 64, m0 = (b >> 3) * 64;
    f32x4 acc[3][2][2];
#pragma unroll
    for (int t = 0; t < 3; t++)
#pragma unroll
      for (int i = 0; i < 2; i++)
#pragma unroll
        for (int j = 0; j < 2; j++) acc[t][i][j] = f32x4{0.f, 0.f, 0.f, 0.f};

    for (int ps = 0; ps < 2; ps++) {
      const bf16_t* A  = ps ? ga.h0b : ga.xhi;
      const bf16_t* Bt = ps ? ga.rkt : ga.kt;
      const int K = ps ? 512 : 256, ld = K;
      for (int k0 = 0; k0 < K; k0 += 64) {
        bf16x8 ar[2], br[6];
#pragma unroll
        for (int r = 0; r < 2; r++) {
          int task = tid + r * 256, row = task >> 3, t = task & 7, sf = t ^ (row & 7);
          ar[r] = *(const bf16x8*)(A + (size_t)(m0 + row) * ld + k0 + sf * 8);
        }
#pragma unroll
        for (int r = 0; r < 6; r++) {
          int task = tid + r * 256;
          int gate = task >> 9, rem = task & 511, o = rem >> 3, t = rem & 7, sf = t ^ (o & 7);
          br[r] = *(const bf16x8*)(Bt + (size_t)(gate * 512 + n0 + o) * ld + k0 + sf * 8);
        }
        __syncthreads();
#pragma unroll
        for (int r = 0; r < 2; r++) {
          int task = tid + r * 256, row = task >> 3, t = task & 7;
          *(bf16x8*)(smA + row * 64 + t * 8) = ar[r];
        }
#pragma unroll
        for (int r = 0; r < 6; r++) {
          int task = tid + r * 256;
          int gate = task >> 9, rem = task & 511, o = rem >> 3, t = rem & 7;
          *(bf16x8*)(smB + (gate * 64 + o) * 64 + t * 8) = br[r];
        }
        __syncthreads();
#pragma unroll
        for (int ks = 0; ks < 2; ks++) {
          bf16x8 af[2];
#pragma unroll
          for (int i = 0; i < 2; i++) {
            int row = wm * 32 + i * 16 + lr;
            af[i] = *(const bf16x8*)(smA + row * 64 + ((ks * 4 + g4) ^ (lr & 7)) * 8);
          }
#pragma unroll
          for (int t = 0; t < 3; t++) {
            bf16x8 bfr[2];
#pragma unroll
            for (int j = 0; j < 2; j++) {
              int row = wn * 32 + j * 16 + lr;
              bfr[j] = *(const bf16x8*)(smB + (t * 64 + row) * 64 + ((ks * 4 + g4) ^ (lr & 7)) * 8);
            }
#pragma unroll
            for (int i = 0; i < 2; i++)
#pragma unroll
              for (int j = 0; j < 2; j++)
                acc[t][i][j] = __builtin_amdgcn_mfma_f32_16x16x32_bf16(af[i], bfr[j], acc[t][i][j], 0, 0, 0);
          }
        }
      }
    }
#pragma unroll
    for (int i = 0; i < 2; i++)
#pragma unroll
      for (int j = 0; j < 2; j++) {
        int col = n0 + wn * 32 + j * 16 + lr;
        float bi = ga.bias[col], bf_ = ga.bias[512 + col], bc = ga.bias[1024 + col];
#pragma unroll
        for (int r = 0; r < 4; r++) {
          int row = m0 + wm * 32 + i * 16 + g4 * 4 + r;
          size_t idx = (size_t)row * 512 + col;
          float iv = sigm(acc[0][i][j][r] + bi);
          float fv = sigm(acc[1][i][j][r] + bf_);
          float cc = sigm(acc[2][i][j][r] + bc);
          float cv = fv * ga.c0[idx] + iv * fast_tanh(cc);
          ga.c_out[idx] = cv;
          ga.tc[idx] = (bf16_t)fast_tanh(cv);
        }
      }
  } else {
    // ---- agg: 6-pass hi/lo GEMM, 64x64 tile ----
    const int b = blockIdx.x - 512;
    const int n0 = (b & 3) * 64, m0 = (b >> 2) * 64;
    f32x4 acc[2][2];
#pragma unroll
    for (int i = 0; i < 2; i++)
#pragma unroll
      for (int j = 0; j < 2; j++) acc[i][j] = f32x4{0.f, 0.f, 0.f, 0.f};

    for (int ps = 0; ps < 6; ps++) {
      const bf16_t* A  = ga.aggA[ps];
      const bf16_t* Bt = ga.aggB[ps];
      for (int k0 = 0; k0 < 256; k0 += 64) {
        bf16x8 ar[2], br[2];
#pragma unroll
        for (int r = 0; r < 2; r++) {
          int task = tid + r * 256, row = task >> 3, t = task & 7, sf = t ^ (row & 7);
          ar[r] = *(const bf16x8*)(A  + (size_t)(m0 + row) * 256 + k0 + sf * 8);
          br[r] = *(const bf16x8*)(Bt + (size_t)(n0 + row) * 256 + k0 + sf * 8);
        }
        __syncthreads();
#pragma unroll
        for (int r = 0; r < 2; r++) {
          int task = tid + r * 256, row = task >> 3, t = task & 7;
          *(bf16x8*)(smA + row * 64 + t * 8) = ar[r];
          *(bf16x8*)(smB + row * 64 + t * 8) = br[r];
        }
        __syncthreads();
#pragma unroll
        for (int ks = 0; ks < 2; ks++) {
          bf16x8 af[2], bfr[2];
#pragma unroll
          for (int i = 0; i < 2; i++) {
            int row = wm * 32 + i * 16 + lr;
            af[i] = *(const bf16x8*)(smA + row * 64 + ((ks * 4 + g4) ^ (lr & 7)) * 8);
          }
#pragma unroll
          for (int j = 0; j < 2; j++) {
            int row = wn * 32 + j * 16 + lr;
            bfr[j] = *(const bf16x8*)(smB + row * 64 + ((ks * 4 + g4) ^ (lr & 7)) * 8);
          }
#pragma unroll
          for (int i = 0; i < 2; i++)
#pragma unroll
            for (int j = 0; j < 2; j++)
              acc[i][j] = __builtin_amdgcn_mfma_f32_16x16x32_bf16(af[i], bfr[j], acc[i][j], 0, 0, 0);
        }
      }
    }
#pragma unroll
    for (int i = 0; i < 2; i++)
#pragma unroll
      for (int j = 0; j < 2; j++) {
        int col = n0 + wn * 32 + j * 16 + lr;
#pragma unroll
        for (int r = 0; r < 4; r++) {
          int row = m0 + wm * 32 + i * 16 + g4 * 4 + r;
          ga.agg[(size_t)row * 256 + col] = acc[i][j][r];
        }
      }
  }
}

// ---------------- Fourier-KAN GEMM v9 (bf16 P output) ----------------
// BM=64, BN=128, q=8 K-split, grid 1024 = 4 blocks/CU. 128 thr = 2 waves
// (wave-tile 64x64, acc[4][4]). B: coalesced reg loads from fcb2; A: shared
// trig-gen into swizzled LDS dbuf. One lgkm-only barrier/iter. LDS 24.8KB.
struct FArgs { const float* agg; const bf16_t* fcb2; bf16_t* P[8]; };

__global__ __launch_bounds__(128, 2) void k_fourier(FArgs fa) {
  __shared__ float  zl[64 * 33];        // 8.4 KB
  __shared__ bf16_t Asm[2][64 * 64];    // 16 KB
  const int tid = threadIdx.x;
  const int bx = blockIdx.x;            // 1024 blocks; q = bx&7 = XCD id
  const int q = bx & 7, nb = (bx >> 3) & 1, mb = bx >> 4;
  const int m0 = mb * 64, n0 = nb * 128, i0 = q * 32;
  const int wv = tid >> 6, lane = tid & 63;
  const int wn = wv;
  const int lr = lane & 15, g4 = lane >> 4;

  // stage z tile [64 rows x 32 i] -> zl (stride 33)
#pragma unroll
  for (int r = 0; r < 4; r++) {
    int task = tid + r * 128, row = task >> 3, seg = task & 7;
    float4 v = *(const float4*)(fa.agg + (size_t)(m0 + row) * 256 + i0 + seg * 4);
    zl[row * 33 + seg * 4 + 0] = v.x;
    zl[row * 33 + seg * 4 + 1] = v.y;
    zl[row * 33 + seg * 4 + 2] = v.z;
    zl[row * 33 + seg * 4 + 3] = v.w;
  }

  // B: coalesced 16B/lane loads from fcb2 (strides: i 16384, nb 8192,
  // wn 4096, j 1024, ks 512, lane*8).
  const bf16_t* pB = fa.fcb2 + (size_t)i0 * 16384 + nb * 8192 + wn * 4096 + lane * 8;
  auto loadB = [&](int i, bf16x8 (&b)[8]) {
#pragma unroll
    for (int ks = 0; ks < 2; ks++)
#pragma unroll
      for (int j = 0; j < 4; j++)
        b[ks * 4 + j] = *(const bf16x8*)(pB + (size_t)i * 16384 + j * 1024 + ks * 512);
  };

  // A trig-gen (shared): row=tid>>1 (0..63), hp=tid&1 -> g4 in {2hp,2hp+1}.
  const int grow = tid >> 1, hp = tid & 1;
  const float* zp = zl + grow * 33;
  const int as0 = grow * 64 + (((2 * hp    ) ^ (grow & 7)) * 8);
  const int as1 = grow * 64 + (((2 * hp + 1) ^ (grow & 7)) * 8);
  const int as2 = grow * 64 + (((4 + 2 * hp) ^ (grow & 7)) * 8);
  const int as3 = grow * 64 + (((5 + 2 * hp) ^ (grow & 7)) * 8);
  auto genA = [&](int i, bf16_t* Ab) {
    float zr = zp[i];
    bf16x8 c0v, c1v, s0v, s1v;
#pragma unroll
    for (int t = 0; t < 8; t++) {
      float r0 = fract_f(zr * (float)(hp * 16 + t + 1));
      float r1 = fract_f(zr * (float)(hp * 16 + 8 + t + 1));
      c0v[t] = (bf16_t)cos_rev(r0); s0v[t] = (bf16_t)sin_rev(r0);
      c1v[t] = (bf16_t)cos_rev(r1); s1v[t] = (bf16_t)sin_rev(r1);
    }
    *(bf16x8*)(Ab + as0) = c0v;
    *(bf16x8*)(Ab + as1) = c1v;
    *(bf16x8*)(Ab + as2) = s0v;
    *(bf16x8*)(Ab + as3) = s1v;
  };

  // fixed A-fragment LDS offsets (rows 0..63)
  int offA[8];
#pragma unroll
  for (int ks = 0; ks < 2; ks++)
#pragma unroll
    for (int i4 = 0; i4 < 4; i4++)
      offA[ks * 4 + i4] = (i4 * 16 + lr) * 64 + ((ks * 4 + g4) ^ (lr & 7)) * 8;

  f32x4 acc[4][4];
#pragma unroll
  for (int i = 0; i < 4; i++)
#pragma unroll
    for (int j = 0; j < 4; j++) acc[i][j] = f32x4{0.f, 0.f, 0.f, 0.f};

  auto domfma = [&](const bf16x8 (&af)[8], const bf16x8 (&b)[8]) {
    __builtin_amdgcn_s_setprio(1);
#pragma unroll
    for (int ks = 0; ks < 2; ks++)
#pragma unroll
      for (int i4 = 0; i4 < 4; i4++)
#pragma unroll
        for (int j = 0; j < 4; j++)
          acc[i4][j] = __builtin_amdgcn_mfma_f32_16x16x32_bf16(af[ks * 4 + i4], b[ks * 4 + j], acc[i4][j], 0, 0, 0);
    __builtin_amdgcn_s_setprio(0);
  };
  auto readA = [&](const bf16_t* Ac, bf16x8 (&af)[8]) {
#pragma unroll
    for (int t = 0; t < 8; t++) af[t] = *(const bf16x8*)(Ac + offA[t]);
  };

  bf16x8 bA_[8], bB_[8];
  __syncthreads();                      // zl visible
  loadB(0, bA_);
  genA(0, Asm[0]);
  asm volatile("s_waitcnt lgkmcnt(0)" ::: "memory");
  __builtin_amdgcn_s_barrier();

#pragma unroll 1
  for (int it = 0; it < 16; it++) {
    const int i = it * 2;
    bf16x8 af[8];
    if (i < 31) loadB(i + 1, bB_);
    readA(Asm[0], af);
    if (i < 31) genA(i + 1, Asm[1]);
    domfma(af, bA_);
    asm volatile("s_waitcnt lgkmcnt(0)" ::: "memory");
    __builtin_amdgcn_s_barrier();
    if (i + 2 < 32) loadB(i + 2, bA_);
    readA(Asm[1], af);
    if (i + 2 < 32) genA(i + 2, Asm[0]);
    domfma(af, bB_);
    asm volatile("s_waitcnt lgkmcnt(0)" ::: "memory");
    __builtin_amdgcn_s_barrier();
  }

  bf16_t* outp = fa.P[q];
#pragma unroll
  for (int i = 0; i < 4; i++)
#pragma unroll
    for (int j = 0; j < 4; j++) {
      int col = n0 + wn * 64 + j * 16 + lr;
#pragma unroll
      for (int r = 0; r < 4; r++) {
        int row = m0 + i * 16 + g4 * 4 + r;
        outp[(size_t)row * 256 + col] = (bf16_t)acc[i][j][r];
      }
    }
}

// ---------------- reduce 8 bf16 K-split partials + new_s epilogue -----------
struct RArgs {
  const bf16_t* P[8];
  const float* fb; const float* tk; const float* s0;
  float* news; bf16_t* sob;
};

__global__ __launch_bounds__(256) void k_freduce(RArgs ra) {
  int stride = gridDim.x * blockDim.x;
  for (int qd = blockIdx.x * blockDim.x + threadIdx.x; qd < 262144; qd += stride) {
    int i = qd * 4, o = i & 255;
    float4 v = {0.f, 0.f, 0.f, 0.f};
#pragma unroll
    for (int c = 0; c < 8; c++) {
      bf16x4 p = *(const bf16x4*)(ra.P[c] + i);
      v.x += (float)p[0]; v.y += (float)p[1]; v.z += (float)p[2]; v.w += (float)p[3];
    }
    v.x += ra.fb[o + 0]; v.y += ra.fb[o + 1]; v.z += ra.fb[o + 2]; v.w += ra.fb[o + 3];
    bf16x4 sb; sb[0] = (bf16_t)v.x; sb[1] = (bf16_t)v.y; sb[2] = (bf16_t)v.z; sb[3] = (bf16_t)v.w;
    *(bf16x4*)(ra.sob + i) = sb;
    float4 s = *(const float4*)(ra.s0 + i);
    float4 ns;
    ns.x = ra.tk[o + 0] * v.x + ra.tk[256 + o + 0] * s.x;
    ns.y = ra.tk[o + 1] * v.y + ra.tk[256 + o + 1] * s.y;
    ns.z = ra.tk[o + 2] * v.z + ra.tk[256 + o + 2] * s.z;
    ns.w = ra.tk[o + 3] * v.w + ra.tk[256 + o + 3] * s.w;
    *(float4*)(ra.news + i) = ns;
  }
}

// ---------------- h = LN(o * tanh(c)), o/tc bf16 ----------------
__global__ __launch_bounds__(256) void k_ln(const bf16_t* __restrict__ o,
                                            const bf16_t* __restrict__ tc,
                                            const float* __restrict__ lg,
                                            const float* __restrict__ lb,
                                            float* __restrict__ h) {
  int b = blockIdx.x, tid = threadIdx.x;
  bf16x2 ov = *(const bf16x2*)(o + (size_t)b * 512 + tid * 2);
  bf16x2 tv = *(const bf16x2*)(tc + (size_t)b * 512 + tid * 2);
  float h0 = (float)ov[0] * (float)tv[0], h1 = (float)ov[1] * (float)tv[1];
  float s = h0 + h1, ss = h0 * h0 + h1 * h1;
#pragma unroll
  for (int off = 32; off; off >>= 1) {
    s += __shfl_xor(s, off);
    ss += __shfl_xor(ss, off);
  }
  __shared__ float red[8];
  int wid = tid >> 6;
  if ((tid & 63) == 0) { red[wid] = s; red[4 + wid] = ss; }
  __syncthreads();
  s = red[0] + red[1] + red[2] + red[3];
  ss = red[4] + red[5] + red[6] + red[7];
  float mu = s * (1.f / 512.f);
  float var = ss * (1.f / 512.f) - mu * mu;
  float rs = rsqrtf(var + 1e-5f);
  int j = tid * 2;
  h[(size_t)b * 512 + j]     = (h0 - mu) * rs * lg[j]     + lb[j];
  h[(size_t)b * 512 + j + 1] = (h1 - mu) * rs * lg[j + 1] + lb[j + 1];
}

// ---------------- launcher ----------------
extern "C" void kernel_launch(void* const* d_in, const int* in_sizes, int n_in,
                              void* d_out, int out_size, void* d_ws, size_t ws_size,
                              hipStream_t stream) {
  const float* x    = (const float*)d_in[0];
  const float* h0   = (const float*)d_in[1];
  const float* c0   = (const float*)d_in[2];
  const float* s0   = (const float*)d_in[3];
  const float* Wk   = (const float*)d_in[4];
  const float* Wr   = (const float*)d_in[5];
  const float* bias = (const float*)d_in[6];
  const float* kx   = (const float*)d_in[7];
  const float* kh   = (const float*)d_in[8];
  const float* tk   = (const float*)d_in[9];
  const float* fc   = (const float*)d_in[10];
  const float* fb   = (const float*)d_in[11];
  const float* aw   = (const float*)d_in[12];
  const float* ab   = (const float*)d_in[13];
  const float* lg   = (const float*)d_in[14];
  const float* lbp  = (const float*)d_in[15];
  float* out = (float*)d_out;
  char* ws = (char*)d_ws;
  auto BF = [&](unsigned long long off) { return (bf16_t*)(ws + off); };
  auto FP = [&](unsigned long long off) { return (float*)(ws + off); };

  // fused conversions + LDS-tiled fcb2 + transposes (4480 blocks)
  k_prep<<<4480, 256, 0, stream>>>(x, h0, s0, fc, Wk, Wr, aw, kx, kh,
                                   BF(O_XHI), BF(O_XLO), BF(O_H0),
                                   BF(O_S0H), BF(O_S0L), BF(O_FCB),
                                   BF(O_KT), BF(O_RKT), BF(O_AWT),
                                   BF(O_KXH), BF(O_KXL), BF(O_KHH), BF(O_KHL));

  // merged gates+cell and agg GEMMs (768 blocks)
  {
    GAArgs ga{};
    ga.xhi = BF(O_XHI); ga.h0b = BF(O_H0); ga.kt = BF(O_KT); ga.rkt = BF(O_RKT);
    ga.bias = bias; ga.c0 = c0; ga.c_out = out + 2097152; ga.tc = BF(O_TC);
    ga.aggA[0] = BF(O_XHI); ga.aggB[0] = BF(O_KXH);
    ga.aggA[1] = BF(O_XHI); ga.aggB[1] = BF(O_KXL);
    ga.aggA[2] = BF(O_XLO); ga.aggB[2] = BF(O_KXH);
    ga.aggA[3] = BF(O_S0H); ga.aggB[3] = BF(O_KHH);
    ga.aggA[4] = BF(O_S0H); ga.aggB[4] = BF(O_KHL);
    ga.aggA[5] = BF(O_S0L); ga.aggB[5] = BF(O_KHH);
    ga.agg = FP(O_AGG);
    k_gatesagg<<<768, 256, 0, stream>>>(ga);
  }

  // Fourier KAN (q=8 K-split, 1024 blocks = 4/CU). P bf16, chunks 0-5
  // overlay XHI/XLO/H0/S0H/S0L (dead after k_gatesagg), 6-7 in O_P3.
  FArgs fa;
  fa.agg = FP(O_AGG); fa.fcb2 = BF(O_FCB);
  for (int c = 0; c < 6; c++) fa.P[c] = BF((unsigned long long)c * 2097152ull);
  fa.P[6] = BF(O_P3);
  fa.P[7] = BF(O_P3 + 2097152ull);
  k_fourier<<<1024, 128, 0, stream>>>(fa);

  // reduce partials, emit new_s (d_out[4M..5M)) + sub_out bf16
  RArgs ra;
  for (int c = 0; c < 8; c++) ra.P[c] = fa.P[c];
  ra.fb = fb; ra.tk = tk; ra.s0 = s0;
  ra.news = out + 4194304; ra.sob = BF(O_SOB);
  k_freduce<<<1024, 256, 0, stream>>>(ra);

  // out-proj GEMM: o = sigmoid(sub_out@agg_w + agg_b), bf16 (O overlays FCB)
  {
    GArgs g{};
    g.p[0] = { BF(O_SOB), BF(O_AWT), 256, 256, 256 };
    g.np = 1; g.bias = ab; g.act = 1;
    g.out = nullptr; g.outb = BF(O_O); g.ldout = 512;
    k_gemm<64, 128><<<dim3(4, 64), 512, 0, stream>>>(g);
  }
  // h = LN(o * tanh(c)) -> d_out[0..2M)
  k_ln<<<4096, 256, 0, stream>>>(BF(O_O), BF(O_TC), lg, lbp, out);
}